// Round 11
// baseline (302.864 us; speedup 1.0000x reference)
//
#include <hip/hip_runtime.h>
#include <hip/hip_bf16.h>

#define NN 50000
#define NE 800000
#define DD 128
#define HH 8
#define CC 16
#define DFF 512
#define ED 16
#define SCAN_NB ((NN + 255) / 256)   // 196
#define BKT 256
#define NBKT ((NN + BKT - 1) / BKT)  // 196
#define EPB 4096

typedef __attribute__((ext_vector_type(8))) short bf16x8;
typedef __attribute__((ext_vector_type(4))) float f32x4;

union U8 { bf16x8 v; unsigned short s[8]; };

__device__ inline unsigned short f2bf(float f) {
    union { float f; unsigned u; } v; v.f = f;
    return (unsigned short)((v.u + 0x7fffu + ((v.u >> 16) & 1u)) >> 16);
}
__device__ inline float bf2f(unsigned s) {
    union { unsigned u; float f; } v; v.u = s << 16;
    return v.f;
}

// ---------------- utility ----------------
__global__ void zero_int_k(int* __restrict__ a, int n) {
    int i = blockIdx.x * 256 + threadIdx.x;
    if (i < n) a[i] = 0;
}

// pack weights into MFMA B-fragment order
__global__ void cvtpack_k(const float* __restrict__ W, unsigned short* __restrict__ Wpk,
                          int K, int N) {
    int idx = blockIdx.x * 256 + threadIdx.x;
    if (idx >= K * N) return;
    int e = idx & 7;
    int l = (idx >> 3) & 63;
    int r = idx >> 9;
    int n16 = N >> 4;
    int jc = r % n16;
    int kt = r / n16;
    int k = kt * 32 + (l >> 4) * 8 + e;
    int n = jc * 16 + (l & 15);
    Wpk[idx] = f2bf(W[(size_t)k * N + n]);
}

// ---------------- CSR build ----------------
__global__ void count_k(const int* __restrict__ dst, int* __restrict__ cnt) {
    int e = blockIdx.x * 256 + threadIdx.x;
    if (e < NE) atomicAdd(&cnt[dst[e]], 1);
}

__global__ void blksum_k(const int* __restrict__ cnt, int* __restrict__ partials) {
    int i = blockIdx.x * 256 + threadIdx.x;
    int v = (i < NN) ? cnt[i] : 0;
#pragma unroll
    for (int m = 1; m < 64; m <<= 1) v += __shfl_xor(v, m, 64);
    __shared__ int ws[4];
    if ((threadIdx.x & 63) == 0) ws[threadIdx.x >> 6] = v;
    __syncthreads();
    if (threadIdx.x == 0) partials[blockIdx.x] = ws[0] + ws[1] + ws[2] + ws[3];
}

__global__ void scanpart_k(int* __restrict__ partials) {
    __shared__ int buf[256];
    int t = threadIdx.x;
    int v = (t < SCAN_NB) ? partials[t] : 0;
    buf[t] = v;
    __syncthreads();
    for (int off = 1; off < 256; off <<= 1) {
        int u = (t >= off) ? buf[t - off] : 0;
        __syncthreads();
        buf[t] += u;
        __syncthreads();
    }
    if (t < SCAN_NB) partials[t] = buf[t] - v;  // exclusive
}

__global__ void scanapply_k(const int* __restrict__ cnt, const int* __restrict__ partials,
                            int* __restrict__ row_start, int* __restrict__ cursor) {
    __shared__ int buf[256];
    int t = threadIdx.x;
    int i = blockIdx.x * 256 + t;
    int v = (i < NN) ? cnt[i] : 0;
    buf[t] = v;
    __syncthreads();
    for (int off = 1; off < 256; off <<= 1) {
        int u = (t >= off) ? buf[t - off] : 0;
        __syncthreads();
        buf[t] += u;
        __syncthreads();
    }
    int excl = buf[t] - v + partials[blockIdx.x];
    if (i < NN) {
        row_start[i] = excl;
        cursor[i] = excl;
        if (i == NN - 1) row_start[NN] = excl + v;
    }
}

__global__ void bucketbase_k(const int* __restrict__ row_start, int* __restrict__ bucket_cursor) {
    int b = blockIdx.x * 256 + threadIdx.x;
    if (b < NBKT) bucket_cursor[b] = row_start[b * BKT];
}

// pass A: bin edges into bucket-major order with LDS-chunked (burst) writes
__global__ __launch_bounds__(256) void bin_k(const int* __restrict__ ei,
                                             int* __restrict__ bucket_cursor,
                                             int2* __restrict__ binned) {
    __shared__ int hist[NBKT];
    __shared__ int base[NBKT];
    int t = threadIdx.x;
    int e0 = blockIdx.x * EPB;
    int eend = e0 + EPB; if (eend > NE) eend = NE;
    if (t < NBKT) hist[t] = 0;
    __syncthreads();
    for (int e = e0 + t; e < eend; e += 256) {
        int d = ei[NE + e];
        atomicAdd(&hist[d >> 8], 1);
    }
    __syncthreads();
    if (t < NBKT) {
        int c = hist[t];
        base[t] = c ? atomicAdd(&bucket_cursor[t], c) : 0;
        hist[t] = 0;   // reuse as local cursor
    }
    __syncthreads();
    for (int e = e0 + t; e < eend; e += 256) {
        int s = ei[e];
        int d = ei[NE + e];
        int b = d >> 8;
        int loc = atomicAdd(&hist[b], 1);
        binned[base[b] + loc] = make_int2(s | ((d & 255) << 16), e);
    }
}

// pass B: per-bucket CSR scatter (SoA outputs: e_src for agg, e_eid for se2)
__global__ __launch_bounds__(256) void csr_scatter_k(const int2* __restrict__ binned,
                                                     const int* __restrict__ row_start,
                                                     int* __restrict__ cursor,
                                                     int* __restrict__ e_src,
                                                     int* __restrict__ e_eid) {
    int b = blockIdx.x;
    int beg = row_start[b * BKT];
    int endNode = (b + 1) * BKT; if (endNode > NN) endNode = NN;
    int end = row_start[endNode];
    for (int p = beg + threadIdx.x; p < end; p += 256) {
        int2 r = binned[p];
        int d = b * BKT + (r.x >> 16);
        int pos = atomicAdd(&cursor[d], 1);
        e_src[pos] = r.x & 0xffff;
        e_eid[pos] = r.y;
    }
}

// ---------------- edge scores, both layers, CSR order ----------------
__global__ void se2_k(const float* __restrict__ ew, const int* __restrict__ e_eid,
                      const float* __restrict__ We1, const float* __restrict__ ae1,
                      const float* __restrict__ We2, const float* __restrict__ ae2,
                      float* __restrict__ s_e1, float* __restrict__ s_e2) {
    __shared__ float A1[ED * HH], A2[ED * HH];
    int t = threadIdx.x;
    if (t < 128) {
        int k = t >> 3, h = t & 7;
        float s = 0.f;
#pragma unroll
        for (int c = 0; c < CC; c++) s += We1[k * DD + h * CC + c] * ae1[h * CC + c];
        A1[t] = s;
    } else {
        int u = t - 128;
        int k = u >> 3, h = u & 7;
        float s = 0.f;
#pragma unroll
        for (int c = 0; c < CC; c++) s += We2[k * DD + h * CC + c] * ae2[h * CC + c];
        A2[u] = s;
    }
    __syncthreads();
    int p = blockIdx.x * 256 + t;
    if (p >= NE) return;
    int eid = e_eid[p];
    const float* ep = &ew[(size_t)eid * ED];
    float4 v0 = *(const float4*)(ep);
    float4 v1 = *(const float4*)(ep + 4);
    float4 v2 = *(const float4*)(ep + 8);
    float4 v3 = *(const float4*)(ep + 12);
    float ev[16] = {v0.x, v0.y, v0.z, v0.w, v1.x, v1.y, v1.z, v1.w,
                    v2.x, v2.y, v2.z, v2.w, v3.x, v3.y, v3.z, v3.w};
    float o1[8] = {0, 0, 0, 0, 0, 0, 0, 0};
    float o2[8] = {0, 0, 0, 0, 0, 0, 0, 0};
#pragma unroll
    for (int k = 0; k < 16; k++) {
        float v = ev[k];
#pragma unroll
        for (int h = 0; h < 8; h++) {
            o1[h] += v * A1[k * 8 + h];
            o2[h] += v * A2[k * 8 + h];
        }
    }
    *(float4*)&s_e1[(size_t)p * 8]     = make_float4(o1[0], o1[1], o1[2], o1[3]);
    *(float4*)&s_e1[(size_t)p * 8 + 4] = make_float4(o1[4], o1[5], o1[6], o1[7]);
    *(float4*)&s_e2[(size_t)p * 8]     = make_float4(o2[0], o2[1], o2[2], o2[3]);
    *(float4*)&s_e2[(size_t)p * 8 + 4] = make_float4(o2[4], o2[5], o2[6], o2[7]);
}

// ---------------- MFMA node GEMM: Ybf = bf16(X @ W), W packed in fragment order ----------------
__global__ __launch_bounds__(256) void gemm_mfma_k(const float* __restrict__ X,
                                                   const unsigned short* __restrict__ Wpk,
                                                   unsigned short* __restrict__ Ybf) {
    __shared__ char Xl[128 * 256];  // bf16 [row][128], XOR-swizzled
    int t = threadIdx.x;
    int nb0 = blockIdx.x * 128;
    for (int c = t; c < 2048; c += 256) {
        int row = c >> 4, cb = c & 15;
        int n = nb0 + row;
        U8 u;
        if (n < NN) {
            const float* xp = &X[(size_t)n * DD + cb * 8];
            float4 a = *(const float4*)xp;
            float4 b = *(const float4*)(xp + 4);
            u.s[0] = f2bf(a.x); u.s[1] = f2bf(a.y); u.s[2] = f2bf(a.z); u.s[3] = f2bf(a.w);
            u.s[4] = f2bf(b.x); u.s[5] = f2bf(b.y); u.s[6] = f2bf(b.z); u.s[7] = f2bf(b.w);
        } else {
#pragma unroll
            for (int q = 0; q < 8; q++) u.s[q] = 0;
        }
        int byte = (row * 256 + cb * 16) ^ ((row & 7) << 4);
        *(bf16x8*)&Xl[byte] = u.v;
    }
    __syncthreads();
    int w = t >> 6, l = t & 63;
    int lrow = l & 15, lq = l >> 4;
    int r0 = (w & 1) * 64, c0 = (w >> 1) * 64;
    f32x4 acc[4][4];
#pragma unroll
    for (int i = 0; i < 4; i++)
#pragma unroll
        for (int j = 0; j < 4; j++) acc[i][j] = (f32x4){0.f, 0.f, 0.f, 0.f};
#pragma unroll
    for (int ks = 0; ks < 4; ks++) {
        int k0 = ks * 32;
        bf16x8 af[4], bq[4];
#pragma unroll
        for (int i = 0; i < 4; i++) {
            int rr = r0 + i * 16 + lrow;
            int byte = (rr * 256 + k0 * 2 + lq * 16) ^ ((rr & 7) << 4);
            af[i] = *(const bf16x8*)&Xl[byte];
        }
#pragma unroll
        for (int j = 0; j < 4; j++) {
            int j16 = (c0 >> 4) + j;
            bq[j] = *(const bf16x8*)&Wpk[(((size_t)ks * 8 + j16) * 64 + l) * 8];
        }
#pragma unroll
        for (int i = 0; i < 4; i++)
#pragma unroll
            for (int j = 0; j < 4; j++)
                acc[i][j] = __builtin_amdgcn_mfma_f32_16x16x32_bf16(af[i], bq[j], acc[i][j], 0, 0, 0);
    }
#pragma unroll
    for (int i = 0; i < 4; i++) {
#pragma unroll
        for (int j = 0; j < 4; j++) {
#pragma unroll
            for (int q = 0; q < 4; q++) {
                int n = nb0 + r0 + i * 16 + lq * 4 + q;
                if (n < NN) Ybf[(size_t)n * DD + c0 + j * 16 + lrow] = f2bf(acc[i][j][q]);
            }
        }
    }
}

// ---------------- s_src/s_dst from bf16 xh ----------------
__global__ void ssd_k(const unsigned short* __restrict__ xh_bf, const float* __restrict__ a_src,
                      const float* __restrict__ a_dst, float* __restrict__ s_src,
                      float* __restrict__ s_dst) {
    __shared__ float as[128], ad[128];
    if (threadIdx.x < 128) {
        as[threadIdx.x] = a_src[threadIdx.x];
        ad[threadIdx.x] = a_dst[threadIdx.x];
    }
    __syncthreads();
    int idx = blockIdx.x * 256 + threadIdx.x;
    if (idx >= NN * HH) return;
    int n = idx >> 3, h = idx & 7;
    const unsigned short* x = &xh_bf[(size_t)n * DD + h * CC];
    U8 u0, u1;
    u0.v = *(const bf16x8*)(x);
    u1.v = *(const bf16x8*)(x + 8);
    float s1 = 0.f, s2 = 0.f;
#pragma unroll
    for (int c = 0; c < 8; c++) {
        float v = bf2f(u0.s[c]);
        s1 += v * as[h * CC + c];
        s2 += v * ad[h * CC + c];
    }
#pragma unroll
    for (int c = 0; c < 8; c++) {
        float v = bf2f(u1.s[c]);
        s1 += v * as[h * CC + 8 + c];
        s2 += v * ad[h * CC + 8 + c];
    }
    s_src[idx] = s1;
    s_dst[idx] = s2;
}

// ---------------- fused aggregation + bias + LayerNorm + leaky + residual ----------------
// 8 edges/iter: lane (h,k) computes score of edge p+k for head h ONCE (no 8x redundancy);
// scores/srcs distributed to the message-fma via shfl. Coalesced e_src/s_src/s_e loads.
__global__ __launch_bounds__(256) void agg_ln_k(const int* __restrict__ row_start,
                                                const int* __restrict__ e_src,
                                                const float* __restrict__ s_src,
                                                const float* __restrict__ s_dst,
                                                const float* __restrict__ s_e,
                                                const unsigned short* __restrict__ xh_bf,
                                                const float* __restrict__ bias,
                                                const float* __restrict__ g,
                                                const float* __restrict__ be,
                                                const float* __restrict__ res,
                                                float* __restrict__ outNf) {
    int wid = (blockIdx.x * 256 + threadIdx.x) >> 6;
    if (wid >= NN) return;
    int lane = threadIdx.x & 63;
    int h = lane >> 3;
    int k = lane & 7;
    unsigned hoff = (unsigned)h << 2;
    unsigned loff = (unsigned)lane << 2;
    const char* xb = (const char*)xh_bf;
    const char* sb = (const char*)s_src;
    const char* eb = (const char*)s_e;
    float sdst = s_dst[wid * 8 + h];
    int beg = row_start[wid], end = row_start[wid + 1];
    float acc0 = 0.f, acc1 = 0.f, zpart = 0.f, ztail = 0.f;
    int p = beg;
    int bcast = h << 3;
    for (; p + 8 <= end; p += 8) {
        // lane's edge: p+k, head h — score computed exactly once
        unsigned q = (unsigned)e_src[p + k];
        float vs = *(const float*)(sb + (q << 5) + hoff);
        float ve = *(const float*)(eb + (((unsigned)(p + k)) << 5) + hoff);  // 256B coalesced
        float a = vs + sdst + ve;
        a = fmaxf(a, 0.2f * a);          // leaky (slope<1) == max(a, 0.2a)
        float esc = __expf(a);
        zpart += esc;
#pragma unroll
        for (int kk = 0; kk < 8; kk++) {
            float sck = __shfl(esc, bcast + kk, 64);     // score(edge p+kk, head h)
            unsigned qk = (unsigned)__shfl((int)q, kk, 64); // src of edge p+kk (lane kk holds it)
            unsigned u = *(const unsigned*)(xb + (qk << 8) + loff);
            acc0 = fmaf(sck, bf2f(u & 0xffffu), acc0);
            acc1 = fmaf(sck, bf2f(u >> 16), acc1);
        }
    }
    for (; p < end; p++) {   // tail <8 edges: old redundant-per-lane path
        unsigned q0 = (unsigned)e_src[p];
        float a0 = *(const float*)(sb + (q0 << 5) + hoff) + sdst + *(const float*)(eb + ((unsigned)p << 5) + hoff);
        unsigned u0 = *(const unsigned*)(xb + (q0 << 8) + loff);
        a0 = fmaxf(a0, 0.2f * a0);
        float e0 = __expf(a0);
        ztail += e0;
        acc0 = fmaf(e0, bf2f(u0 & 0xffffu), acc0);
        acc1 = fmaf(e0, bf2f(u0 >> 16), acc1);
    }
    // reduce zpart over the 8 k-slots within each h-group (masks 1,2,4 stay in-group)
    float z = zpart;
    z += __shfl_xor(z, 1, 64);
    z += __shfl_xor(z, 2, 64);
    z += __shfl_xor(z, 4, 64);
    z += ztail;
    float inv = 1.f / (z + 1e-16f);
    float2 b = *(const float2*)&bias[lane * 2];
    float x0 = acc0 * inv + b.x;
    float x1 = acc1 * inv + b.y;
    float s = x0 + x1;
    float q = x0 * x0 + x1 * x1;
#pragma unroll
    for (int m = 1; m < 64; m <<= 1) {
        s += __shfl_xor(s, m, 64);
        q += __shfl_xor(q, m, 64);
    }
    float mu = s * (1.f / 128.f);
    float var = (q - 128.f * mu * mu) * (1.f / 127.f);
    float sd = sqrtf(fmaxf(var, 0.f));
    float invs = 1.f / (sd + 1e-6f);
    float2 gg = *(const float2*)&g[lane * 2];
    float2 bb = *(const float2*)&be[lane * 2];
    float y0 = gg.x * (x0 - mu) * invs + bb.x;
    float y1 = gg.y * (x1 - mu) * invs + bb.y;
    y0 = (y0 > 0.f) ? y0 : 0.01f * y0;
    y1 = (y1 > 0.f) ? y1 : 0.01f * y1;
    float2 r = *(const float2*)&res[(size_t)wid * DD + lane * 2];
    *(float2*)&outNf[(size_t)wid * DD + lane * 2] = make_float2(r.x + y0, r.y + y1);
}

// ---------------- bias + LayerNorm(ddof=1) + leaky_relu + residual ----------------
__global__ __launch_bounds__(256) void ln_k(const float* __restrict__ hin,
                                            const float* __restrict__ bias,
                                            const float* __restrict__ g,
                                            const float* __restrict__ be,
                                            const float* __restrict__ res,
                                            float* __restrict__ out) {
    int wid = (blockIdx.x * 256 + threadIdx.x) >> 6;
    if (wid >= NN) return;
    int lane = threadIdx.x & 63;
    float2 x = *(const float2*)&hin[(size_t)wid * DD + lane * 2];
    float2 b = *(const float2*)&bias[lane * 2];
    x.x += b.x;
    x.y += b.y;
    float s = x.x + x.y;
    float q = x.x * x.x + x.y * x.y;
#pragma unroll
    for (int m = 1; m < 64; m <<= 1) {
        s += __shfl_xor(s, m, 64);
        q += __shfl_xor(q, m, 64);
    }
    float mu = s * (1.f / 128.f);
    float var = (q - 128.f * mu * mu) * (1.f / 127.f);
    float sd = sqrtf(fmaxf(var, 0.f));
    float inv = 1.f / (sd + 1e-6f);
    float2 gg = *(const float2*)&g[lane * 2];
    float2 bb = *(const float2*)&be[lane * 2];
    float y0 = gg.x * (x.x - mu) * inv + bb.x;
    float y1 = gg.y * (x.y - mu) * inv + bb.y;
    y0 = (y0 > 0.f) ? y0 : 0.01f * y0;
    y1 = (y1 > 0.f) ? y1 : 0.01f * y1;
    float2 r = *(const float2*)&res[(size_t)wid * DD + lane * 2];
    *(float2*)&out[(size_t)wid * DD + lane * 2] = make_float2(r.x + y0, r.y + y1);
}

// ---------------- fused MFMA FFN: 64 nodes/block, hidden in 4 chunks of 128 ----------------
__global__ __launch_bounds__(256) void ffn_mfma_k(const float* __restrict__ X,
                                                  const unsigned short* __restrict__ Wf1pk,
                                                  const float* __restrict__ bf1,
                                                  const unsigned short* __restrict__ Wf2pk,
                                                  float* __restrict__ out) {
    __shared__ char Xl[64 * 256];   // bf16 [64][128] swizzled, 16KB
    __shared__ char Hl[64 * 256];   // bf16 [64][128] swizzled, 16KB
    int t = threadIdx.x;
    int nb0 = blockIdx.x * 64;
    for (int c = t; c < 1024; c += 256) {
        int row = c >> 4, cb = c & 15;
        int n = nb0 + row;
        U8 u;
        if (n < NN) {
            const float* xp = &X[(size_t)n * DD + cb * 8];
            float4 a = *(const float4*)xp;
            float4 b = *(const float4*)(xp + 4);
            u.s[0] = f2bf(a.x); u.s[1] = f2bf(a.y); u.s[2] = f2bf(a.z); u.s[3] = f2bf(a.w);
            u.s[4] = f2bf(b.x); u.s[5] = f2bf(b.y); u.s[6] = f2bf(b.z); u.s[7] = f2bf(b.w);
        } else {
#pragma unroll
            for (int q = 0; q < 8; q++) u.s[q] = 0;
        }
        int byte = (row * 256 + cb * 16) ^ ((row & 7) << 4);
        *(bf16x8*)&Xl[byte] = u.v;
    }
    __syncthreads();
    int w = t >> 6, l = t & 63;
    int lrow = l & 15, lq = l >> 4;
    int wr = (w & 1) * 32;
    int wc = (w >> 1) * 64;
    f32x4 oacc[2][4];
#pragma unroll
    for (int i = 0; i < 2; i++)
#pragma unroll
        for (int j = 0; j < 4; j++) oacc[i][j] = (f32x4){0.f, 0.f, 0.f, 0.f};

#pragma unroll
    for (int ch = 0; ch < 4; ch++) {
        int hc0 = ch * 128;
        f32x4 a[2][4];
#pragma unroll
        for (int i = 0; i < 2; i++)
#pragma unroll
            for (int j = 0; j < 4; j++) a[i][j] = (f32x4){0.f, 0.f, 0.f, 0.f};
#pragma unroll
        for (int ks = 0; ks < 4; ks++) {
            int k0 = ks * 32;
            bf16x8 af[2], bq[4];
#pragma unroll
            for (int i = 0; i < 2; i++) {
                int rr = wr + i * 16 + lrow;
                int byte = (rr * 256 + k0 * 2 + lq * 16) ^ ((rr & 7) << 4);
                af[i] = *(const bf16x8*)&Xl[byte];
            }
#pragma unroll
            for (int j = 0; j < 4; j++) {
                int j16 = ch * 8 + (wc >> 4) + j;
                bq[j] = *(const bf16x8*)&Wf1pk[(((size_t)ks * 32 + j16) * 64 + l) * 8];
            }
#pragma unroll
            for (int i = 0; i < 2; i++)
#pragma unroll
                for (int j = 0; j < 4; j++)
                    a[i][j] = __builtin_amdgcn_mfma_f32_16x16x32_bf16(af[i], bq[j], a[i][j], 0, 0, 0);
        }
        float bias[4];
#pragma unroll
        for (int j = 0; j < 4; j++) bias[j] = bf1[hc0 + wc + j * 16 + lrow];
#pragma unroll
        for (int i = 0; i < 2; i++) {
#pragma unroll
            for (int j = 0; j < 4; j++) {
#pragma unroll
                for (int q = 0; q < 4; q++) {
                    float v = fmaxf(a[i][j][q] + bias[j], 0.f);
                    int row = wr + i * 16 + lq * 4 + q;
                    int col = wc + j * 16 + lrow;
                    int byte = (row * 256 + col * 2) ^ ((row & 7) << 4);
                    *(unsigned short*)&Hl[byte] = f2bf(v);
                }
            }
        }
        __syncthreads();
#pragma unroll
        for (int ks = 0; ks < 4; ks++) {
            int k0 = ks * 32;
            bf16x8 hf[2], b2[4];
#pragma unroll
            for (int i = 0; i < 2; i++) {
                int rr = wr + i * 16 + lrow;
                int byte = (rr * 256 + k0 * 2 + lq * 16) ^ ((rr & 7) << 4);
                hf[i] = *(const bf16x8*)&Hl[byte];
            }
#pragma unroll
            for (int j = 0; j < 4; j++) {
                int kt = ch * 4 + ks;
                int j16 = (wc >> 4) + j;
                b2[j] = *(const bf16x8*)&Wf2pk[(((size_t)kt * 8 + j16) * 64 + l) * 8];
            }
#pragma unroll
            for (int i = 0; i < 2; i++)
#pragma unroll
                for (int j = 0; j < 4; j++)
                    oacc[i][j] = __builtin_amdgcn_mfma_f32_16x16x32_bf16(hf[i], b2[j], oacc[i][j], 0, 0, 0);
        }
        __syncthreads();
    }
#pragma unroll
    for (int i = 0; i < 2; i++) {
#pragma unroll
        for (int j = 0; j < 4; j++) {
#pragma unroll
            for (int q = 0; q < 4; q++) {
                int n = nb0 + wr + i * 16 + lq * 4 + q;
                if (n < NN) out[(size_t)n * DD + wc + j * 16 + lrow] = oacc[i][j][q];
            }
        }
    }
}

extern "C" void kernel_launch(void* const* d_in, const int* in_sizes, int n_in,
                              void* d_out, int out_size, void* d_ws, size_t ws_size,
                              hipStream_t stream) {
    const float* nf  = (const float*)d_in[0];
    const int*   ei  = (const int*)d_in[1];
    const float* ew  = (const float*)d_in[2];
    const float* W1  = (const float*)d_in[3];
    const float* as1 = (const float*)d_in[4];
    const float* ad1 = (const float*)d_in[5];
    const float* We1 = (const float*)d_in[6];
    const float* ae1 = (const float*)d_in[7];
    const float* b1  = (const float*)d_in[8];
    const float* g1  = (const float*)d_in[9];
    const float* be1 = (const float*)d_in[10];
    const float* W2  = (const float*)d_in[11];
    const float* as2 = (const float*)d_in[12];
    const float* ad2 = (const float*)d_in[13];
    const float* We2 = (const float*)d_in[14];
    const float* ae2 = (const float*)d_in[15];
    const float* b2  = (const float*)d_in[16];
    const float* g2  = (const float*)d_in[17];
    const float* be2 = (const float*)d_in[18];
    const float* Wf1 = (const float*)d_in[19];
    const float* bf1 = (const float*)d_in[20];
    const float* Wf2 = (const float*)d_in[21];
    const float* bf2 = (const float*)d_in[22];
    const float* g3  = (const float*)d_in[23];
    const float* be3 = (const float*)d_in[24];
    float* out = (float*)d_out;

    char* p = (char*)d_ws;
    auto alloc = [&](size_t bytes) {
        char* r = p;
        p += (bytes + 255) & ~(size_t)255;
        return r;
    };
    float* nf_cur = (float*)alloc((size_t)NN * DD * 4);
    unsigned short* xh_bf = (unsigned short*)alloc((size_t)NN * DD * 2);
    float* s_e1   = (float*)alloc((size_t)NE * HH * 4);
    float* s_e2   = (float*)alloc((size_t)NE * HH * 4);
    float* s_src  = (float*)alloc((size_t)NN * HH * 4);
    float* s_dst  = (float*)alloc((size_t)NN * HH * 4);
    int* row_start = (int*)alloc((size_t)(NN + 1) * 4);
    int* cnt       = (int*)alloc((size_t)NN * 4);
    int* cursor    = (int*)alloc((size_t)NN * 4);
    int* partials  = (int*)alloc((size_t)SCAN_NB * 4);
    int* bucket_cursor = (int*)alloc((size_t)NBKT * 4);
    int2* binned   = (int2*)alloc((size_t)NE * 8);
    int* e_src     = (int*)alloc((size_t)NE * 4);
    int* e_eid     = (int*)alloc((size_t)NE * 4);
    unsigned short* W1pk  = (unsigned short*)alloc((size_t)DD * DD * 2);
    unsigned short* W2pk  = (unsigned short*)alloc((size_t)DD * DD * 2);
    unsigned short* Wf1pk = (unsigned short*)alloc((size_t)DD * DFF * 2);
    unsigned short* Wf2pk = (unsigned short*)alloc((size_t)DFF * DD * 2);
    float* h_out = s_e1;   // alias: s_e1 dead after layer-2 agg; sizes equal (NE*8*4 == NN*128*4)

    int ebl = (NE + 255) / 256;
    int nbl = (NN + 255) / 256;

    // weight pack+cvt (tiny, once): fragment-order bf16
    cvtpack_k<<<(DD * DD + 255) / 256, 256, 0, stream>>>(W1, W1pk, DD, DD);
    cvtpack_k<<<(DD * DD + 255) / 256, 256, 0, stream>>>(W2, W2pk, DD, DD);
    cvtpack_k<<<(DD * DFF + 255) / 256, 256, 0, stream>>>(Wf1, Wf1pk, DD, DFF);
    cvtpack_k<<<(DD * DFF + 255) / 256, 256, 0, stream>>>(Wf2, Wf2pk, DFF, DD);

    // CSR build (hierarchical scan)
    zero_int_k<<<nbl, 256, 0, stream>>>(cnt, NN);
    count_k<<<ebl, 256, 0, stream>>>(ei + NE, cnt);
    blksum_k<<<SCAN_NB, 256, 0, stream>>>(cnt, partials);
    scanpart_k<<<1, 256, 0, stream>>>(partials);
    scanapply_k<<<SCAN_NB, 256, 0, stream>>>(cnt, partials, row_start, cursor);

    // two-level binned scatter (kills cross-XCD write amplification)
    bucketbase_k<<<(NBKT + 255) / 256, 256, 0, stream>>>(row_start, bucket_cursor);
    bin_k<<<(NE + EPB - 1) / EPB, 256, 0, stream>>>(ei, bucket_cursor, binned);
    csr_scatter_k<<<NBKT, 256, 0, stream>>>(binned, row_start, cursor, e_src, e_eid);

    // edge scores for BOTH layers, coalesced writes
    se2_k<<<ebl, 256, 0, stream>>>(ew, e_eid, We1, ae1, We2, ae2, s_e1, s_e2);

    int gbl = (NN + 127) / 128;
    int wbl = (NN + 3) / 4;
    int sbl = (NN * HH + 255) / 256;

    // ---- GAT layer 1 ----
    gemm_mfma_k<<<gbl, 256, 0, stream>>>(nf, W1pk, xh_bf);
    ssd_k<<<sbl, 256, 0, stream>>>(xh_bf, as1, ad1, s_src, s_dst);
    agg_ln_k<<<wbl, 256, 0, stream>>>(row_start, e_src, s_src, s_dst, s_e1, xh_bf,
                                      b1, g1, be1, nf, nf_cur);

    // ---- GAT layer 2 ----
    gemm_mfma_k<<<gbl, 256, 0, stream>>>(nf_cur, W2pk, xh_bf);
    ssd_k<<<sbl, 256, 0, stream>>>(xh_bf, as2, ad2, s_src, s_dst);
    agg_ln_k<<<wbl, 256, 0, stream>>>(row_start, e_src, s_src, s_dst, s_e2, xh_bf,
                                      b2, g2, be2, nf_cur, nf_cur);

    // ---- FFN ----
    ffn_mfma_k<<<(NN + 63) / 64, 256, 0, stream>>>(nf_cur, Wf1pk, bf1, Wf2pk, h_out);
    ln_k<<<wbl, 256, 0, stream>>>(h_out, bf2, g3, be3, nf_cur, out);
}

// Round 12
// 295.356 us; speedup vs baseline: 1.0254x; 1.0254x over previous
//
#include <hip/hip_runtime.h>
#include <hip/hip_bf16.h>

#define NN 50000
#define NE 800000
#define DD 128
#define HH 8
#define CC 16
#define DFF 512
#define ED 16
#define SCAN_NB ((NN + 255) / 256)   // 196
#define BKT 256
#define NBKT ((NN + BKT - 1) / BKT)  // 196
#define EPB 4096

typedef __attribute__((ext_vector_type(8))) short bf16x8;
typedef __attribute__((ext_vector_type(4))) float f32x4;

union U8 { bf16x8 v; unsigned short s[8]; };

__device__ inline unsigned short f2bf(float f) {
    union { float f; unsigned u; } v; v.f = f;
    return (unsigned short)((v.u + 0x7fffu + ((v.u >> 16) & 1u)) >> 16);
}
__device__ inline float bf2f(unsigned s) {
    union { unsigned u; float f; } v; v.u = s << 16;
    return v.f;
}

// ---------------- utility ----------------
__global__ void zero_int_k(int* __restrict__ a, int n) {
    int i = blockIdx.x * 256 + threadIdx.x;
    if (i < n) a[i] = 0;
}

// pack weights into MFMA B-fragment order
__global__ void cvtpack_k(const float* __restrict__ W, unsigned short* __restrict__ Wpk,
                          int K, int N) {
    int idx = blockIdx.x * 256 + threadIdx.x;
    if (idx >= K * N) return;
    int e = idx & 7;
    int l = (idx >> 3) & 63;
    int r = idx >> 9;
    int n16 = N >> 4;
    int jc = r % n16;
    int kt = r / n16;
    int k = kt * 32 + (l >> 4) * 8 + e;
    int n = jc * 16 + (l & 15);
    Wpk[idx] = f2bf(W[(size_t)k * N + n]);
}

// ---------------- CSR build ----------------
__global__ void count_k(const int* __restrict__ dst, int* __restrict__ cnt) {
    int e = blockIdx.x * 256 + threadIdx.x;
    if (e < NE) atomicAdd(&cnt[dst[e]], 1);
}

__global__ void blksum_k(const int* __restrict__ cnt, int* __restrict__ partials) {
    int i = blockIdx.x * 256 + threadIdx.x;
    int v = (i < NN) ? cnt[i] : 0;
#pragma unroll
    for (int m = 1; m < 64; m <<= 1) v += __shfl_xor(v, m, 64);
    __shared__ int ws[4];
    if ((threadIdx.x & 63) == 0) ws[threadIdx.x >> 6] = v;
    __syncthreads();
    if (threadIdx.x == 0) partials[blockIdx.x] = ws[0] + ws[1] + ws[2] + ws[3];
}

__global__ void scanpart_k(int* __restrict__ partials) {
    __shared__ int buf[256];
    int t = threadIdx.x;
    int v = (t < SCAN_NB) ? partials[t] : 0;
    buf[t] = v;
    __syncthreads();
    for (int off = 1; off < 256; off <<= 1) {
        int u = (t >= off) ? buf[t - off] : 0;
        __syncthreads();
        buf[t] += u;
        __syncthreads();
    }
    if (t < SCAN_NB) partials[t] = buf[t] - v;  // exclusive
}

__global__ void scanapply_k(const int* __restrict__ cnt, const int* __restrict__ partials,
                            int* __restrict__ row_start, int* __restrict__ cursor) {
    __shared__ int buf[256];
    int t = threadIdx.x;
    int i = blockIdx.x * 256 + t;
    int v = (i < NN) ? cnt[i] : 0;
    buf[t] = v;
    __syncthreads();
    for (int off = 1; off < 256; off <<= 1) {
        int u = (t >= off) ? buf[t - off] : 0;
        __syncthreads();
        buf[t] += u;
        __syncthreads();
    }
    int excl = buf[t] - v + partials[blockIdx.x];
    if (i < NN) {
        row_start[i] = excl;
        cursor[i] = excl;
        if (i == NN - 1) row_start[NN] = excl + v;
    }
}

__global__ void bucketbase_k(const int* __restrict__ row_start, int* __restrict__ bucket_cursor) {
    int b = blockIdx.x * 256 + threadIdx.x;
    if (b < NBKT) bucket_cursor[b] = row_start[b * BKT];
}

// pass A: bin edges into bucket-major order with LDS-chunked (burst) writes
__global__ __launch_bounds__(256) void bin_k(const int* __restrict__ ei,
                                             int* __restrict__ bucket_cursor,
                                             int2* __restrict__ binned) {
    __shared__ int hist[NBKT];
    __shared__ int base[NBKT];
    int t = threadIdx.x;
    int e0 = blockIdx.x * EPB;
    int eend = e0 + EPB; if (eend > NE) eend = NE;
    if (t < NBKT) hist[t] = 0;
    __syncthreads();
    for (int e = e0 + t; e < eend; e += 256) {
        int d = ei[NE + e];
        atomicAdd(&hist[d >> 8], 1);
    }
    __syncthreads();
    if (t < NBKT) {
        int c = hist[t];
        base[t] = c ? atomicAdd(&bucket_cursor[t], c) : 0;
        hist[t] = 0;   // reuse as local cursor
    }
    __syncthreads();
    for (int e = e0 + t; e < eend; e += 256) {
        int s = ei[e];
        int d = ei[NE + e];
        int b = d >> 8;
        int loc = atomicAdd(&hist[b], 1);
        binned[base[b] + loc] = make_int2(s | ((d & 255) << 16), e);
    }
}

// pass B: per-bucket CSR scatter (SoA outputs: e_src for agg, e_eid for se2)
__global__ __launch_bounds__(256) void csr_scatter_k(const int2* __restrict__ binned,
                                                     const int* __restrict__ row_start,
                                                     int* __restrict__ cursor,
                                                     int* __restrict__ e_src,
                                                     int* __restrict__ e_eid) {
    int b = blockIdx.x;
    int beg = row_start[b * BKT];
    int endNode = (b + 1) * BKT; if (endNode > NN) endNode = NN;
    int end = row_start[endNode];
    for (int p = beg + threadIdx.x; p < end; p += 256) {
        int2 r = binned[p];
        int d = b * BKT + (r.x >> 16);
        int pos = atomicAdd(&cursor[d], 1);
        e_src[pos] = r.x & 0xffff;
        e_eid[pos] = r.y;
    }
}

// ---------------- edge scores, both layers, CSR order, bf16 output ----------------
__global__ void se2_k(const float* __restrict__ ew, const int* __restrict__ e_eid,
                      const float* __restrict__ We1, const float* __restrict__ ae1,
                      const float* __restrict__ We2, const float* __restrict__ ae2,
                      unsigned short* __restrict__ s_e1, unsigned short* __restrict__ s_e2) {
    __shared__ float A1[ED * HH], A2[ED * HH];
    int t = threadIdx.x;
    if (t < 128) {
        int k = t >> 3, h = t & 7;
        float s = 0.f;
#pragma unroll
        for (int c = 0; c < CC; c++) s += We1[k * DD + h * CC + c] * ae1[h * CC + c];
        A1[t] = s;
    } else {
        int u = t - 128;
        int k = u >> 3, h = u & 7;
        float s = 0.f;
#pragma unroll
        for (int c = 0; c < CC; c++) s += We2[k * DD + h * CC + c] * ae2[h * CC + c];
        A2[u] = s;
    }
    __syncthreads();
    int p = blockIdx.x * 256 + t;
    if (p >= NE) return;
    int eid = e_eid[p];
    const float* ep = &ew[(size_t)eid * ED];
    float4 v0 = *(const float4*)(ep);
    float4 v1 = *(const float4*)(ep + 4);
    float4 v2 = *(const float4*)(ep + 8);
    float4 v3 = *(const float4*)(ep + 12);
    float ev[16] = {v0.x, v0.y, v0.z, v0.w, v1.x, v1.y, v1.z, v1.w,
                    v2.x, v2.y, v2.z, v2.w, v3.x, v3.y, v3.z, v3.w};
    float o1[8] = {0, 0, 0, 0, 0, 0, 0, 0};
    float o2[8] = {0, 0, 0, 0, 0, 0, 0, 0};
#pragma unroll
    for (int k = 0; k < 16; k++) {
        float v = ev[k];
#pragma unroll
        for (int h = 0; h < 8; h++) {
            o1[h] += v * A1[k * 8 + h];
            o2[h] += v * A2[k * 8 + h];
        }
    }
    U8 w1, w2;
#pragma unroll
    for (int h = 0; h < 8; h++) { w1.s[h] = f2bf(o1[h]); w2.s[h] = f2bf(o2[h]); }
    *(bf16x8*)&s_e1[(size_t)p * 8] = w1.v;
    *(bf16x8*)&s_e2[(size_t)p * 8] = w2.v;
}

// ---------------- MFMA node GEMM: Ybf = bf16(X @ W), W packed in fragment order ----------------
__global__ __launch_bounds__(256) void gemm_mfma_k(const float* __restrict__ X,
                                                   const unsigned short* __restrict__ Wpk,
                                                   unsigned short* __restrict__ Ybf) {
    __shared__ char Xl[128 * 256];  // bf16 [row][128], XOR-swizzled
    int t = threadIdx.x;
    int nb0 = blockIdx.x * 128;
    for (int c = t; c < 2048; c += 256) {
        int row = c >> 4, cb = c & 15;
        int n = nb0 + row;
        U8 u;
        if (n < NN) {
            const float* xp = &X[(size_t)n * DD + cb * 8];
            float4 a = *(const float4*)xp;
            float4 b = *(const float4*)(xp + 4);
            u.s[0] = f2bf(a.x); u.s[1] = f2bf(a.y); u.s[2] = f2bf(a.z); u.s[3] = f2bf(a.w);
            u.s[4] = f2bf(b.x); u.s[5] = f2bf(b.y); u.s[6] = f2bf(b.z); u.s[7] = f2bf(b.w);
        } else {
#pragma unroll
            for (int q = 0; q < 8; q++) u.s[q] = 0;
        }
        int byte = (row * 256 + cb * 16) ^ ((row & 7) << 4);
        *(bf16x8*)&Xl[byte] = u.v;
    }
    __syncthreads();
    int w = t >> 6, l = t & 63;
    int lrow = l & 15, lq = l >> 4;
    int r0 = (w & 1) * 64, c0 = (w >> 1) * 64;
    f32x4 acc[4][4];
#pragma unroll
    for (int i = 0; i < 4; i++)
#pragma unroll
        for (int j = 0; j < 4; j++) acc[i][j] = (f32x4){0.f, 0.f, 0.f, 0.f};
#pragma unroll
    for (int ks = 0; ks < 4; ks++) {
        int k0 = ks * 32;
        bf16x8 af[4], bq[4];
#pragma unroll
        for (int i = 0; i < 4; i++) {
            int rr = r0 + i * 16 + lrow;
            int byte = (rr * 256 + k0 * 2 + lq * 16) ^ ((rr & 7) << 4);
            af[i] = *(const bf16x8*)&Xl[byte];
        }
#pragma unroll
        for (int j = 0; j < 4; j++) {
            int j16 = (c0 >> 4) + j;
            bq[j] = *(const bf16x8*)&Wpk[(((size_t)ks * 8 + j16) * 64 + l) * 8];
        }
#pragma unroll
        for (int i = 0; i < 4; i++)
#pragma unroll
            for (int j = 0; j < 4; j++)
                acc[i][j] = __builtin_amdgcn_mfma_f32_16x16x32_bf16(af[i], bq[j], acc[i][j], 0, 0, 0);
    }
#pragma unroll
    for (int i = 0; i < 4; i++) {
#pragma unroll
        for (int j = 0; j < 4; j++) {
#pragma unroll
            for (int q = 0; q < 4; q++) {
                int n = nb0 + r0 + i * 16 + lq * 4 + q;
                if (n < NN) Ybf[(size_t)n * DD + c0 + j * 16 + lrow] = f2bf(acc[i][j][q]);
            }
        }
    }
}

// ---------------- s_src(bf16)/s_dst(f32) from bf16 xh ----------------
__global__ void ssd_k(const unsigned short* __restrict__ xh_bf, const float* __restrict__ a_src,
                      const float* __restrict__ a_dst, unsigned short* __restrict__ s_srcb,
                      float* __restrict__ s_dst) {
    __shared__ float as[128], ad[128];
    if (threadIdx.x < 128) {
        as[threadIdx.x] = a_src[threadIdx.x];
        ad[threadIdx.x] = a_dst[threadIdx.x];
    }
    __syncthreads();
    int idx = blockIdx.x * 256 + threadIdx.x;
    if (idx >= NN * HH) return;
    int n = idx >> 3, h = idx & 7;
    const unsigned short* x = &xh_bf[(size_t)n * DD + h * CC];
    U8 u0, u1;
    u0.v = *(const bf16x8*)(x);
    u1.v = *(const bf16x8*)(x + 8);
    float s1 = 0.f, s2 = 0.f;
#pragma unroll
    for (int c = 0; c < 8; c++) {
        float v = bf2f(u0.s[c]);
        s1 += v * as[h * CC + c];
        s2 += v * ad[h * CC + c];
    }
#pragma unroll
    for (int c = 0; c < 8; c++) {
        float v = bf2f(u1.s[c]);
        s1 += v * as[h * CC + 8 + c];
        s2 += v * ad[h * CC + 8 + c];
    }
    s_srcb[idx] = f2bf(s1);
    s_dst[idx] = s2;
}

// ---------------- fused aggregation + bias + LayerNorm + leaky + residual ----------------
// 8 edges/iter: lane (h,k) computes score of edge p+k for head h ONCE; bf16 score streams.
__global__ __launch_bounds__(256) void agg_ln_k(const int* __restrict__ row_start,
                                                const int* __restrict__ e_src,
                                                const unsigned short* __restrict__ s_srcb,
                                                const float* __restrict__ s_dst,
                                                const unsigned short* __restrict__ s_eb,
                                                const unsigned short* __restrict__ xh_bf,
                                                const float* __restrict__ bias,
                                                const float* __restrict__ g,
                                                const float* __restrict__ be,
                                                const float* __restrict__ res,
                                                float* __restrict__ outNf) {
    int wid = (blockIdx.x * 256 + threadIdx.x) >> 6;
    if (wid >= NN) return;
    int lane = threadIdx.x & 63;
    int h = lane >> 3;
    int k = lane & 7;
    unsigned h2 = (unsigned)h << 1;
    unsigned loff = (unsigned)lane << 2;
    const char* xb = (const char*)xh_bf;
    const char* sb = (const char*)s_srcb;
    const char* eb = (const char*)s_eb;
    float sdst = s_dst[wid * 8 + h];
    int beg = row_start[wid], end = row_start[wid + 1];
    float acc0 = 0.f, acc1 = 0.f, zpart = 0.f, ztail = 0.f;
    int p = beg;
    int bcast = h << 3;
    for (; p + 8 <= end; p += 8) {
        unsigned q = (unsigned)e_src[p + k];
        float vs = bf2f(*(const unsigned short*)(sb + (q << 4) + h2));
        float ve = bf2f(*(const unsigned short*)(eb + (((unsigned)(p + k)) << 4) + h2));
        float a = vs + sdst + ve;
        a = fmaxf(a, 0.2f * a);
        float esc = __expf(a);
        zpart += esc;
#pragma unroll
        for (int kk = 0; kk < 8; kk++) {
            float sck = __shfl(esc, bcast + kk, 64);
            unsigned qk = (unsigned)__shfl((int)q, kk, 64);
            unsigned u = *(const unsigned*)(xb + (qk << 8) + loff);
            acc0 = fmaf(sck, bf2f(u & 0xffffu), acc0);
            acc1 = fmaf(sck, bf2f(u >> 16), acc1);
        }
    }
    for (; p < end; p++) {
        unsigned q0 = (unsigned)e_src[p];
        float a0 = bf2f(*(const unsigned short*)(sb + (q0 << 4) + h2)) + sdst
                 + bf2f(*(const unsigned short*)(eb + ((unsigned)p << 4) + h2));
        unsigned u0 = *(const unsigned*)(xb + (q0 << 8) + loff);
        a0 = fmaxf(a0, 0.2f * a0);
        float e0 = __expf(a0);
        ztail += e0;
        acc0 = fmaf(e0, bf2f(u0 & 0xffffu), acc0);
        acc1 = fmaf(e0, bf2f(u0 >> 16), acc1);
    }
    float z = zpart;
    z += __shfl_xor(z, 1, 64);
    z += __shfl_xor(z, 2, 64);
    z += __shfl_xor(z, 4, 64);
    z += ztail;
    float inv = 1.f / (z + 1e-16f);
    float2 b = *(const float2*)&bias[lane * 2];
    float x0 = acc0 * inv + b.x;
    float x1 = acc1 * inv + b.y;
    float s = x0 + x1;
    float q = x0 * x0 + x1 * x1;
#pragma unroll
    for (int m = 1; m < 64; m <<= 1) {
        s += __shfl_xor(s, m, 64);
        q += __shfl_xor(q, m, 64);
    }
    float mu = s * (1.f / 128.f);
    float var = (q - 128.f * mu * mu) * (1.f / 127.f);
    float sd = sqrtf(fmaxf(var, 0.f));
    float invs = 1.f / (sd + 1e-6f);
    float2 gg = *(const float2*)&g[lane * 2];
    float2 bb = *(const float2*)&be[lane * 2];
    float y0 = gg.x * (x0 - mu) * invs + bb.x;
    float y1 = gg.y * (x1 - mu) * invs + bb.y;
    y0 = (y0 > 0.f) ? y0 : 0.01f * y0;
    y1 = (y1 > 0.f) ? y1 : 0.01f * y1;
    float2 r = *(const float2*)&res[(size_t)wid * DD + lane * 2];
    *(float2*)&outNf[(size_t)wid * DD + lane * 2] = make_float2(r.x + y0, r.y + y1);
}

// ---------------- fused MFMA FFN + bias + LayerNorm + leaky + residual ----------------
// 64 nodes/block; hidden in 4 chunks of 128; output LN fused via LDS reuse.
__global__ __launch_bounds__(256) void ffn_ln_k(const float* __restrict__ X,
                                                const unsigned short* __restrict__ Wf1pk,
                                                const float* __restrict__ bf1,
                                                const unsigned short* __restrict__ Wf2pk,
                                                const float* __restrict__ bf2,
                                                const float* __restrict__ g3,
                                                const float* __restrict__ be3,
                                                float* __restrict__ out) {
    __shared__ char LDSBUF[32768];   // Xl[0:16K) | Hl[16K:32K); reused as Ol f32[64][128]
    char* Xl = LDSBUF;
    char* Hl = LDSBUF + 16384;
    int t = threadIdx.x;
    int nb0 = blockIdx.x * 64;
    for (int c = t; c < 1024; c += 256) {
        int row = c >> 4, cb = c & 15;
        int n = nb0 + row;
        U8 u;
        if (n < NN) {
            const float* xp = &X[(size_t)n * DD + cb * 8];
            float4 a = *(const float4*)xp;
            float4 b = *(const float4*)(xp + 4);
            u.s[0] = f2bf(a.x); u.s[1] = f2bf(a.y); u.s[2] = f2bf(a.z); u.s[3] = f2bf(a.w);
            u.s[4] = f2bf(b.x); u.s[5] = f2bf(b.y); u.s[6] = f2bf(b.z); u.s[7] = f2bf(b.w);
        } else {
#pragma unroll
            for (int q = 0; q < 8; q++) u.s[q] = 0;
        }
        int byte = (row * 256 + cb * 16) ^ ((row & 7) << 4);
        *(bf16x8*)&Xl[byte] = u.v;
    }
    __syncthreads();
    int w = t >> 6, l = t & 63;
    int lrow = l & 15, lq = l >> 4;
    int wr = (w & 1) * 32;
    int wc = (w >> 1) * 64;
    f32x4 oacc[2][4];
#pragma unroll
    for (int i = 0; i < 2; i++)
#pragma unroll
        for (int j = 0; j < 4; j++) oacc[i][j] = (f32x4){0.f, 0.f, 0.f, 0.f};

#pragma unroll
    for (int ch = 0; ch < 4; ch++) {
        int hc0 = ch * 128;
        f32x4 a[2][4];
#pragma unroll
        for (int i = 0; i < 2; i++)
#pragma unroll
            for (int j = 0; j < 4; j++) a[i][j] = (f32x4){0.f, 0.f, 0.f, 0.f};
#pragma unroll
        for (int ks = 0; ks < 4; ks++) {
            int k0 = ks * 32;
            bf16x8 af[2], bq[4];
#pragma unroll
            for (int i = 0; i < 2; i++) {
                int rr = wr + i * 16 + lrow;
                int byte = (rr * 256 + k0 * 2 + lq * 16) ^ ((rr & 7) << 4);
                af[i] = *(const bf16x8*)&Xl[byte];
            }
#pragma unroll
            for (int j = 0; j < 4; j++) {
                int j16 = ch * 8 + (wc >> 4) + j;
                bq[j] = *(const bf16x8*)&Wf1pk[(((size_t)ks * 32 + j16) * 64 + l) * 8];
            }
#pragma unroll
            for (int i = 0; i < 2; i++)
#pragma unroll
                for (int j = 0; j < 4; j++)
                    a[i][j] = __builtin_amdgcn_mfma_f32_16x16x32_bf16(af[i], bq[j], a[i][j], 0, 0, 0);
        }
        float bias[4];
#pragma unroll
        for (int j = 0; j < 4; j++) bias[j] = bf1[hc0 + wc + j * 16 + lrow];
#pragma unroll
        for (int i = 0; i < 2; i++) {
#pragma unroll
            for (int j = 0; j < 4; j++) {
#pragma unroll
                for (int q = 0; q < 4; q++) {
                    float v = fmaxf(a[i][j][q] + bias[j], 0.f);
                    int row = wr + i * 16 + lq * 4 + q;
                    int col = wc + j * 16 + lrow;
                    int byte = (row * 256 + col * 2) ^ ((row & 7) << 4);
                    *(unsigned short*)&Hl[byte] = f2bf(v);
                }
            }
        }
        __syncthreads();
#pragma unroll
        for (int ks = 0; ks < 4; ks++) {
            int k0 = ks * 32;
            bf16x8 hf[2], b2[4];
#pragma unroll
            for (int i = 0; i < 2; i++) {
                int rr = wr + i * 16 + lrow;
                int byte = (rr * 256 + k0 * 2 + lq * 16) ^ ((rr & 7) << 4);
                hf[i] = *(const bf16x8*)&Hl[byte];
            }
#pragma unroll
            for (int j = 0; j < 4; j++) {
                int kt = ch * 4 + ks;
                int j16 = (wc >> 4) + j;
                b2[j] = *(const bf16x8*)&Wf2pk[(((size_t)kt * 8 + j16) * 64 + l) * 8];
            }
#pragma unroll
            for (int i = 0; i < 2; i++)
#pragma unroll
                for (int j = 0; j < 4; j++)
                    oacc[i][j] = __builtin_amdgcn_mfma_f32_16x16x32_bf16(hf[i], b2[j], oacc[i][j], 0, 0, 0);
        }
        __syncthreads();
    }
    // ---- epilogue: stage f32 output in LDS (reuse buffer), then wave-per-row LN ----
    float* Ol = (float*)LDSBUF;
#pragma unroll
    for (int i = 0; i < 2; i++) {
#pragma unroll
        for (int j = 0; j < 4; j++) {
#pragma unroll
            for (int q = 0; q < 4; q++) {
                int row = wr + i * 16 + lq * 4 + q;
                int col = wc + j * 16 + lrow;
                Ol[row * 128 + col] = oacc[i][j][q];
            }
        }
    }
    __syncthreads();
    float2 b = *(const float2*)&bf2[l * 2];
    float2 gg = *(const float2*)&g3[l * 2];
    float2 bb = *(const float2*)&be3[l * 2];
    for (int rr = w * 16; rr < w * 16 + 16; rr++) {
        int n = nb0 + rr;
        if (n >= NN) continue;   // wave-uniform branch
        float x0 = Ol[rr * 128 + l * 2]     + b.x;
        float x1 = Ol[rr * 128 + l * 2 + 1] + b.y;
        float s = x0 + x1;
        float q = x0 * x0 + x1 * x1;
#pragma unroll
        for (int m = 1; m < 64; m <<= 1) {
            s += __shfl_xor(s, m, 64);
            q += __shfl_xor(q, m, 64);
        }
        float mu = s * (1.f / 128.f);
        float var = (q - 128.f * mu * mu) * (1.f / 127.f);
        float sd = sqrtf(fmaxf(var, 0.f));
        float inv = 1.f / (sd + 1e-6f);
        float y0 = gg.x * (x0 - mu) * inv + bb.x;
        float y1 = gg.y * (x1 - mu) * inv + bb.y;
        y0 = (y0 > 0.f) ? y0 : 0.01f * y0;
        y1 = (y1 > 0.f) ? y1 : 0.01f * y1;
        float2 r = *(const float2*)&X[(size_t)n * DD + l * 2];
        *(float2*)&out[(size_t)n * DD + l * 2] = make_float2(r.x + y0, r.y + y1);
    }
}

extern "C" void kernel_launch(void* const* d_in, const int* in_sizes, int n_in,
                              void* d_out, int out_size, void* d_ws, size_t ws_size,
                              hipStream_t stream) {
    const float* nf  = (const float*)d_in[0];
    const int*   ei  = (const int*)d_in[1];
    const float* ew  = (const float*)d_in[2];
    const float* W1  = (const float*)d_in[3];
    const float* as1 = (const float*)d_in[4];
    const float* ad1 = (const float*)d_in[5];
    const float* We1 = (const float*)d_in[6];
    const float* ae1 = (const float*)d_in[7];
    const float* b1  = (const float*)d_in[8];
    const float* g1  = (const float*)d_in[9];
    const float* be1 = (const float*)d_in[10];
    const float* W2  = (const float*)d_in[11];
    const float* as2 = (const float*)d_in[12];
    const float* ad2 = (const float*)d_in[13];
    const float* We2 = (const float*)d_in[14];
    const float* ae2 = (const float*)d_in[15];
    const float* b2  = (const float*)d_in[16];
    const float* g2  = (const float*)d_in[17];
    const float* be2 = (const float*)d_in[18];
    const float* Wf1 = (const float*)d_in[19];
    const float* bf1 = (const float*)d_in[20];
    const float* Wf2 = (const float*)d_in[21];
    const float* bf2 = (const float*)d_in[22];
    const float* g3  = (const float*)d_in[23];
    const float* be3 = (const float*)d_in[24];
    float* out = (float*)d_out;

    char* p = (char*)d_ws;
    auto alloc = [&](size_t bytes) {
        char* r = p;
        p += (bytes + 255) & ~(size_t)255;
        return r;
    };
    float* nf_cur = (float*)alloc((size_t)NN * DD * 4);
    unsigned short* xh_bf = (unsigned short*)alloc((size_t)NN * DD * 2);
    unsigned short* s_e1  = (unsigned short*)alloc((size_t)NE * HH * 2);
    unsigned short* s_e2  = (unsigned short*)alloc((size_t)NE * HH * 2);
    unsigned short* s_srcb = (unsigned short*)alloc((size_t)NN * HH * 2);
    float* s_dst  = (float*)alloc((size_t)NN * HH * 4);
    int* row_start = (int*)alloc((size_t)(NN + 1) * 4);
    int* cnt       = (int*)alloc((size_t)NN * 4);
    int* cursor    = (int*)alloc((size_t)NN * 4);
    int* partials  = (int*)alloc((size_t)SCAN_NB * 4);
    int* bucket_cursor = (int*)alloc((size_t)NBKT * 4);
    int2* binned   = (int2*)alloc((size_t)NE * 8);
    int* e_src     = (int*)alloc((size_t)NE * 4);
    int* e_eid     = (int*)alloc((size_t)NE * 4);
    unsigned short* W1pk  = (unsigned short*)alloc((size_t)DD * DD * 2);
    unsigned short* W2pk  = (unsigned short*)alloc((size_t)DD * DD * 2);
    unsigned short* Wf1pk = (unsigned short*)alloc((size_t)DD * DFF * 2);
    unsigned short* Wf2pk = (unsigned short*)alloc((size_t)DFF * DD * 2);

    int ebl = (NE + 255) / 256;
    int nbl = (NN + 255) / 256;

    // weight pack+cvt (tiny, once): fragment-order bf16
    cvtpack_k<<<(DD * DD + 255) / 256, 256, 0, stream>>>(W1, W1pk, DD, DD);
    cvtpack_k<<<(DD * DD + 255) / 256, 256, 0, stream>>>(W2, W2pk, DD, DD);
    cvtpack_k<<<(DD * DFF + 255) / 256, 256, 0, stream>>>(Wf1, Wf1pk, DD, DFF);
    cvtpack_k<<<(DD * DFF + 255) / 256, 256, 0, stream>>>(Wf2, Wf2pk, DFF, DD);

    // CSR build (hierarchical scan)
    zero_int_k<<<nbl, 256, 0, stream>>>(cnt, NN);
    count_k<<<ebl, 256, 0, stream>>>(ei + NE, cnt);
    blksum_k<<<SCAN_NB, 256, 0, stream>>>(cnt, partials);
    scanpart_k<<<1, 256, 0, stream>>>(partials);
    scanapply_k<<<SCAN_NB, 256, 0, stream>>>(cnt, partials, row_start, cursor);

    // two-level binned scatter (kills cross-XCD write amplification)
    bucketbase_k<<<(NBKT + 255) / 256, 256, 0, stream>>>(row_start, bucket_cursor);
    bin_k<<<(NE + EPB - 1) / EPB, 256, 0, stream>>>(ei, bucket_cursor, binned);
    csr_scatter_k<<<NBKT, 256, 0, stream>>>(binned, row_start, cursor, e_src, e_eid);

    // edge scores for BOTH layers, coalesced bf16 writes
    se2_k<<<ebl, 256, 0, stream>>>(ew, e_eid, We1, ae1, We2, ae2, s_e1, s_e2);

    int gbl = (NN + 127) / 128;
    int wbl = (NN + 3) / 4;
    int sbl = (NN * HH + 255) / 256;

    // ---- GAT layer 1 ----
    gemm_mfma_k<<<gbl, 256, 0, stream>>>(nf, W1pk, xh_bf);
    ssd_k<<<sbl, 256, 0, stream>>>(xh_bf, as1, ad1, s_srcb, s_dst);
    agg_ln_k<<<wbl, 256, 0, stream>>>(row_start, e_src, s_srcb, s_dst, s_e1, xh_bf,
                                      b1, g1, be1, nf, nf_cur);

    // ---- GAT layer 2 ----
    gemm_mfma_k<<<gbl, 256, 0, stream>>>(nf_cur, W2pk, xh_bf);
    ssd_k<<<sbl, 256, 0, stream>>>(xh_bf, as2, ad2, s_srcb, s_dst);
    agg_ln_k<<<wbl, 256, 0, stream>>>(row_start, e_src, s_srcb, s_dst, s_e2, xh_bf,
                                      b2, g2, be2, nf_cur, nf_cur);

    // ---- FFN + final LN (fused) ----
    ffn_ln_k<<<(NN + 63) / 64, 256, 0, stream>>>(nf_cur, Wf1pk, bf1, Wf2pk,
                                                 bf2, g3, be3, out);
}

// Round 13
// 285.891 us; speedup vs baseline: 1.0594x; 1.0331x over previous
//
#include <hip/hip_runtime.h>
#include <hip/hip_bf16.h>

#define NN 50000
#define NE 800000
#define DD 128
#define HH 8
#define CC 16
#define DFF 512
#define ED 16
#define SCAN_NB ((NN + 255) / 256)   // 196
#define BKT 256
#define NBKT ((NN + BKT - 1) / BKT)  // 196
#define EPB 4096

typedef __attribute__((ext_vector_type(8))) short bf16x8;
typedef __attribute__((ext_vector_type(4))) float f32x4;

union U8 { bf16x8 v; unsigned short s[8]; };

__device__ inline unsigned short f2bf(float f) {
    union { float f; unsigned u; } v; v.f = f;
    return (unsigned short)((v.u + 0x7fffu + ((v.u >> 16) & 1u)) >> 16);
}
__device__ inline float bf2f(unsigned s) {
    union { unsigned u; float f; } v; v.u = s << 16;
    return v.f;
}

// ---------------- utility ----------------
__global__ void zero_int_k(int* __restrict__ a, int n) {
    int i = blockIdx.x * 256 + threadIdx.x;
    if (i < n) a[i] = 0;
}

// pack weights into MFMA B-fragment order
__global__ void cvtpack_k(const float* __restrict__ W, unsigned short* __restrict__ Wpk,
                          int K, int N) {
    int idx = blockIdx.x * 256 + threadIdx.x;
    if (idx >= K * N) return;
    int e = idx & 7;
    int l = (idx >> 3) & 63;
    int r = idx >> 9;
    int n16 = N >> 4;
    int jc = r % n16;
    int kt = r / n16;
    int k = kt * 32 + (l >> 4) * 8 + e;
    int n = jc * 16 + (l & 15);
    Wpk[idx] = f2bf(W[(size_t)k * N + n]);
}

// ---------------- CSR build ----------------
__global__ void count_k(const int* __restrict__ dst, int* __restrict__ cnt) {
    int e = blockIdx.x * 256 + threadIdx.x;
    if (e < NE) atomicAdd(&cnt[dst[e]], 1);
}

__global__ void blksum_k(const int* __restrict__ cnt, int* __restrict__ partials) {
    int i = blockIdx.x * 256 + threadIdx.x;
    int v = (i < NN) ? cnt[i] : 0;
#pragma unroll
    for (int m = 1; m < 64; m <<= 1) v += __shfl_xor(v, m, 64);
    __shared__ int ws[4];
    if ((threadIdx.x & 63) == 0) ws[threadIdx.x >> 6] = v;
    __syncthreads();
    if (threadIdx.x == 0) partials[blockIdx.x] = ws[0] + ws[1] + ws[2] + ws[3];
}

__global__ void scanpart_k(int* __restrict__ partials) {
    __shared__ int buf[256];
    int t = threadIdx.x;
    int v = (t < SCAN_NB) ? partials[t] : 0;
    buf[t] = v;
    __syncthreads();
    for (int off = 1; off < 256; off <<= 1) {
        int u = (t >= off) ? buf[t - off] : 0;
        __syncthreads();
        buf[t] += u;
        __syncthreads();
    }
    if (t < SCAN_NB) partials[t] = buf[t] - v;  // exclusive
}

__global__ void scanapply_k(const int* __restrict__ cnt, const int* __restrict__ partials,
                            int* __restrict__ row_start, int* __restrict__ cursor) {
    __shared__ int buf[256];
    int t = threadIdx.x;
    int i = blockIdx.x * 256 + t;
    int v = (i < NN) ? cnt[i] : 0;
    buf[t] = v;
    __syncthreads();
    for (int off = 1; off < 256; off <<= 1) {
        int u = (t >= off) ? buf[t - off] : 0;
        __syncthreads();
        buf[t] += u;
        __syncthreads();
    }
    int excl = buf[t] - v + partials[blockIdx.x];
    if (i < NN) {
        row_start[i] = excl;
        cursor[i] = excl;
        if (i == NN - 1) row_start[NN] = excl + v;
    }
}

__global__ void bucketbase_k(const int* __restrict__ row_start, int* __restrict__ bucket_cursor) {
    int b = blockIdx.x * 256 + threadIdx.x;
    if (b < NBKT) bucket_cursor[b] = row_start[b * BKT];
}

// pass A: bin edges into bucket-major order with LDS-chunked (burst) writes
__global__ __launch_bounds__(256) void bin_k(const int* __restrict__ ei,
                                             int* __restrict__ bucket_cursor,
                                             int2* __restrict__ binned) {
    __shared__ int hist[NBKT];
    __shared__ int base[NBKT];
    int t = threadIdx.x;
    int e0 = blockIdx.x * EPB;
    int eend = e0 + EPB; if (eend > NE) eend = NE;
    if (t < NBKT) hist[t] = 0;
    __syncthreads();
    for (int e = e0 + t; e < eend; e += 256) {
        int d = ei[NE + e];
        atomicAdd(&hist[d >> 8], 1);
    }
    __syncthreads();
    if (t < NBKT) {
        int c = hist[t];
        base[t] = c ? atomicAdd(&bucket_cursor[t], c) : 0;
        hist[t] = 0;   // reuse as local cursor
    }
    __syncthreads();
    for (int e = e0 + t; e < eend; e += 256) {
        int s = ei[e];
        int d = ei[NE + e];
        int b = d >> 8;
        int loc = atomicAdd(&hist[b], 1);
        binned[base[b] + loc] = make_int2(s | ((d & 255) << 16), e);
    }
}

// pass B: per-bucket CSR scatter (SoA outputs: e_src for agg, e_eid for se2)
__global__ __launch_bounds__(256) void csr_scatter_k(const int2* __restrict__ binned,
                                                     const int* __restrict__ row_start,
                                                     int* __restrict__ cursor,
                                                     int* __restrict__ e_src,
                                                     int* __restrict__ e_eid) {
    int b = blockIdx.x;
    int beg = row_start[b * BKT];
    int endNode = (b + 1) * BKT; if (endNode > NN) endNode = NN;
    int end = row_start[endNode];
    for (int p = beg + threadIdx.x; p < end; p += 256) {
        int2 r = binned[p];
        int d = b * BKT + (r.x >> 16);
        int pos = atomicAdd(&cursor[d], 1);
        e_src[pos] = r.x & 0xffff;
        e_eid[pos] = r.y;
    }
}

// ---------------- edge scores, both layers, CSR order, bf16 output ----------------
__global__ void se2_k(const float* __restrict__ ew, const int* __restrict__ e_eid,
                      const float* __restrict__ We1, const float* __restrict__ ae1,
                      const float* __restrict__ We2, const float* __restrict__ ae2,
                      unsigned short* __restrict__ s_e1, unsigned short* __restrict__ s_e2) {
    __shared__ float A1[ED * HH], A2[ED * HH];
    int t = threadIdx.x;
    if (t < 128) {
        int k = t >> 3, h = t & 7;
        float s = 0.f;
#pragma unroll
        for (int c = 0; c < CC; c++) s += We1[k * DD + h * CC + c] * ae1[h * CC + c];
        A1[t] = s;
    } else {
        int u = t - 128;
        int k = u >> 3, h = u & 7;
        float s = 0.f;
#pragma unroll
        for (int c = 0; c < CC; c++) s += We2[k * DD + h * CC + c] * ae2[h * CC + c];
        A2[u] = s;
    }
    __syncthreads();
    int p = blockIdx.x * 256 + t;
    if (p >= NE) return;
    int eid = e_eid[p];
    const float* ep = &ew[(size_t)eid * ED];
    float4 v0 = *(const float4*)(ep);
    float4 v1 = *(const float4*)(ep + 4);
    float4 v2 = *(const float4*)(ep + 8);
    float4 v3 = *(const float4*)(ep + 12);
    float ev[16] = {v0.x, v0.y, v0.z, v0.w, v1.x, v1.y, v1.z, v1.w,
                    v2.x, v2.y, v2.z, v2.w, v3.x, v3.y, v3.z, v3.w};
    float o1[8] = {0, 0, 0, 0, 0, 0, 0, 0};
    float o2[8] = {0, 0, 0, 0, 0, 0, 0, 0};
#pragma unroll
    for (int k = 0; k < 16; k++) {
        float v = ev[k];
#pragma unroll
        for (int h = 0; h < 8; h++) {
            o1[h] += v * A1[k * 8 + h];
            o2[h] += v * A2[k * 8 + h];
        }
    }
    U8 w1, w2;
#pragma unroll
    for (int h = 0; h < 8; h++) { w1.s[h] = f2bf(o1[h]); w2.s[h] = f2bf(o2[h]); }
    *(bf16x8*)&s_e1[(size_t)p * 8] = w1.v;
    *(bf16x8*)&s_e2[(size_t)p * 8] = w2.v;
}

// ---------------- MFMA node GEMM: Ybf = bf16(X @ W), W packed in fragment order ----------------
__global__ __launch_bounds__(256) void gemm_mfma_k(const float* __restrict__ X,
                                                   const unsigned short* __restrict__ Wpk,
                                                   unsigned short* __restrict__ Ybf) {
    __shared__ char Xl[128 * 256];  // bf16 [row][128], XOR-swizzled
    int t = threadIdx.x;
    int nb0 = blockIdx.x * 128;
    for (int c = t; c < 2048; c += 256) {
        int row = c >> 4, cb = c & 15;
        int n = nb0 + row;
        U8 u;
        if (n < NN) {
            const float* xp = &X[(size_t)n * DD + cb * 8];
            float4 a = *(const float4*)xp;
            float4 b = *(const float4*)(xp + 4);
            u.s[0] = f2bf(a.x); u.s[1] = f2bf(a.y); u.s[2] = f2bf(a.z); u.s[3] = f2bf(a.w);
            u.s[4] = f2bf(b.x); u.s[5] = f2bf(b.y); u.s[6] = f2bf(b.z); u.s[7] = f2bf(b.w);
        } else {
#pragma unroll
            for (int q = 0; q < 8; q++) u.s[q] = 0;
        }
        int byte = (row * 256 + cb * 16) ^ ((row & 7) << 4);
        *(bf16x8*)&Xl[byte] = u.v;
    }
    __syncthreads();
    int w = t >> 6, l = t & 63;
    int lrow = l & 15, lq = l >> 4;
    int r0 = (w & 1) * 64, c0 = (w >> 1) * 64;
    f32x4 acc[4][4];
#pragma unroll
    for (int i = 0; i < 4; i++)
#pragma unroll
        for (int j = 0; j < 4; j++) acc[i][j] = (f32x4){0.f, 0.f, 0.f, 0.f};
#pragma unroll
    for (int ks = 0; ks < 4; ks++) {
        int k0 = ks * 32;
        bf16x8 af[4], bq[4];
#pragma unroll
        for (int i = 0; i < 4; i++) {
            int rr = r0 + i * 16 + lrow;
            int byte = (rr * 256 + k0 * 2 + lq * 16) ^ ((rr & 7) << 4);
            af[i] = *(const bf16x8*)&Xl[byte];
        }
#pragma unroll
        for (int j = 0; j < 4; j++) {
            int j16 = (c0 >> 4) + j;
            bq[j] = *(const bf16x8*)&Wpk[(((size_t)ks * 8 + j16) * 64 + l) * 8];
        }
#pragma unroll
        for (int i = 0; i < 4; i++)
#pragma unroll
            for (int j = 0; j < 4; j++)
                acc[i][j] = __builtin_amdgcn_mfma_f32_16x16x32_bf16(af[i], bq[j], acc[i][j], 0, 0, 0);
    }
#pragma unroll
    for (int i = 0; i < 4; i++) {
#pragma unroll
        for (int j = 0; j < 4; j++) {
#pragma unroll
            for (int q = 0; q < 4; q++) {
                int n = nb0 + r0 + i * 16 + lq * 4 + q;
                if (n < NN) Ybf[(size_t)n * DD + c0 + j * 16 + lrow] = f2bf(acc[i][j][q]);
            }
        }
    }
}

// ---------------- s_src(bf16)/s_dst(f32) from bf16 xh ----------------
__global__ void ssd_k(const unsigned short* __restrict__ xh_bf, const float* __restrict__ a_src,
                      const float* __restrict__ a_dst, unsigned short* __restrict__ s_srcb,
                      float* __restrict__ s_dst) {
    __shared__ float as[128], ad[128];
    if (threadIdx.x < 128) {
        as[threadIdx.x] = a_src[threadIdx.x];
        ad[threadIdx.x] = a_dst[threadIdx.x];
    }
    __syncthreads();
    int idx = blockIdx.x * 256 + threadIdx.x;
    if (idx >= NN * HH) return;
    int n = idx >> 3, h = idx & 7;
    const unsigned short* x = &xh_bf[(size_t)n * DD + h * CC];
    U8 u0, u1;
    u0.v = *(const bf16x8*)(x);
    u1.v = *(const bf16x8*)(x + 8);
    float s1 = 0.f, s2 = 0.f;
#pragma unroll
    for (int c = 0; c < 8; c++) {
        float v = bf2f(u0.s[c]);
        s1 += v * as[h * CC + c];
        s2 += v * ad[h * CC + c];
    }
#pragma unroll
    for (int c = 0; c < 8; c++) {
        float v = bf2f(u1.s[c]);
        s1 += v * as[h * CC + 8 + c];
        s2 += v * ad[h * CC + 8 + c];
    }
    s_srcb[idx] = f2bf(s1);
    s_dst[idx] = s2;
}

// ---------------- fused aggregation + bias + LayerNorm + leaky + residual ----------------
__global__ __launch_bounds__(256) void agg_ln_k(const int* __restrict__ row_start,
                                                const int* __restrict__ e_src,
                                                const unsigned short* __restrict__ s_srcb,
                                                const float* __restrict__ s_dst,
                                                const unsigned short* __restrict__ s_eb,
                                                const unsigned short* __restrict__ xh_bf,
                                                const float* __restrict__ bias,
                                                const float* __restrict__ g,
                                                const float* __restrict__ be,
                                                const float* __restrict__ res,
                                                float* __restrict__ outNf) {
    int wid = (blockIdx.x * 256 + threadIdx.x) >> 6;
    if (wid >= NN) return;
    int lane = threadIdx.x & 63;
    int h = lane >> 3;
    int k = lane & 7;
    unsigned h2 = (unsigned)h << 1;
    unsigned loff = (unsigned)lane << 2;
    const char* xb = (const char*)xh_bf;
    const char* sb = (const char*)s_srcb;
    const char* eb = (const char*)s_eb;
    float sdst = s_dst[wid * 8 + h];
    int beg = row_start[wid], end = row_start[wid + 1];
    float acc0 = 0.f, acc1 = 0.f, zpart = 0.f, ztail = 0.f;
    int p = beg;
    int bcast = h << 3;
    for (; p + 8 <= end; p += 8) {
        unsigned q = (unsigned)e_src[p + k];
        float vs = bf2f(*(const unsigned short*)(sb + (q << 4) + h2));
        float ve = bf2f(*(const unsigned short*)(eb + (((unsigned)(p + k)) << 4) + h2));
        float a = vs + sdst + ve;
        a = fmaxf(a, 0.2f * a);
        float esc = __expf(a);
        zpart += esc;
#pragma unroll
        for (int kk = 0; kk < 8; kk++) {
            float sck = __shfl(esc, bcast + kk, 64);
            unsigned qk = (unsigned)__shfl((int)q, kk, 64);
            unsigned u = *(const unsigned*)(xb + (qk << 8) + loff);
            acc0 = fmaf(sck, bf2f(u & 0xffffu), acc0);
            acc1 = fmaf(sck, bf2f(u >> 16), acc1);
        }
    }
    for (; p < end; p++) {
        unsigned q0 = (unsigned)e_src[p];
        float a0 = bf2f(*(const unsigned short*)(sb + (q0 << 4) + h2)) + sdst
                 + bf2f(*(const unsigned short*)(eb + ((unsigned)p << 4) + h2));
        unsigned u0 = *(const unsigned*)(xb + (q0 << 8) + loff);
        a0 = fmaxf(a0, 0.2f * a0);
        float e0 = __expf(a0);
        ztail += e0;
        acc0 = fmaf(e0, bf2f(u0 & 0xffffu), acc0);
        acc1 = fmaf(e0, bf2f(u0 >> 16), acc1);
    }
    float z = zpart;
    z += __shfl_xor(z, 1, 64);
    z += __shfl_xor(z, 2, 64);
    z += __shfl_xor(z, 4, 64);
    z += ztail;
    float inv = 1.f / (z + 1e-16f);
    float2 b = *(const float2*)&bias[lane * 2];
    float x0 = acc0 * inv + b.x;
    float x1 = acc1 * inv + b.y;
    float s = x0 + x1;
    float q = x0 * x0 + x1 * x1;
#pragma unroll
    for (int m = 1; m < 64; m <<= 1) {
        s += __shfl_xor(s, m, 64);
        q += __shfl_xor(q, m, 64);
    }
    float mu = s * (1.f / 128.f);
    float var = (q - 128.f * mu * mu) * (1.f / 127.f);
    float sd = sqrtf(fmaxf(var, 0.f));
    float invs = 1.f / (sd + 1e-6f);
    float2 gg = *(const float2*)&g[lane * 2];
    float2 bb = *(const float2*)&be[lane * 2];
    float y0 = gg.x * (x0 - mu) * invs + bb.x;
    float y1 = gg.y * (x1 - mu) * invs + bb.y;
    y0 = (y0 > 0.f) ? y0 : 0.01f * y0;
    y1 = (y1 > 0.f) ? y1 : 0.01f * y1;
    float2 r = *(const float2*)&res[(size_t)wid * DD + lane * 2];
    *(float2*)&outNf[(size_t)wid * DD + lane * 2] = make_float2(r.x + y0, r.y + y1);
}

// ---------------- barrier-free fused FFN + LN: wave-private 16-node slices ----------------
// 64 nodes/block, 4 waves; wave w owns rows nb0+w*16..+15 with private Xl/Hl LDS regions.
// No __syncthreads anywhere: all LDS deps are same-wave (compiler lgkmcnt).
// Epilogue LN fully in-register (4 shfl_xor per quantity within 16-lane groups).
__global__ __launch_bounds__(256) void ffn_ln_k(const float* __restrict__ X,
                                                const unsigned short* __restrict__ Wf1pk,
                                                const float* __restrict__ bf1,
                                                const unsigned short* __restrict__ Wf2pk,
                                                const float* __restrict__ bf2,
                                                const float* __restrict__ g3,
                                                const float* __restrict__ be3,
                                                float* __restrict__ out) {
    __shared__ char LDSBUF[32768];   // per-wave: Xl at w*4096, Hl at 16384+w*4096
    int t = threadIdx.x;
    int w = t >> 6, l = t & 63;
    int lrow = l & 15, lq = l >> 4;
    int nb0 = blockIdx.x * 64;
    int rowbase = nb0 + w * 16;
    char* Xw = LDSBUF + w * 4096;
    char* Hw = LDSBUF + 16384 + w * 4096;

    // wave-private staging: 16 rows x 128 cols bf16, swizzled
    for (int c = l; c < 256; c += 64) {
        int row = c >> 4, cb = c & 15;
        int n = rowbase + row;
        U8 u;
        if (n < NN) {
            const float* xp = &X[(size_t)n * DD + cb * 8];
            float4 a = *(const float4*)xp;
            float4 b = *(const float4*)(xp + 4);
            u.s[0] = f2bf(a.x); u.s[1] = f2bf(a.y); u.s[2] = f2bf(a.z); u.s[3] = f2bf(a.w);
            u.s[4] = f2bf(b.x); u.s[5] = f2bf(b.y); u.s[6] = f2bf(b.z); u.s[7] = f2bf(b.w);
        } else {
#pragma unroll
            for (int q = 0; q < 8; q++) u.s[q] = 0;
        }
        int byte = (row * 256 + cb * 16) ^ ((row & 7) << 4);
        *(bf16x8*)&Xw[byte] = u.v;
    }

    f32x4 oacc[8];
#pragma unroll
    for (int j = 0; j < 8; j++) oacc[j] = (f32x4){0.f, 0.f, 0.f, 0.f};

#pragma unroll
    for (int ch = 0; ch < 4; ch++) {
        // ---- phase A: H_chunk(16 x 128) = relu(Xw @ Wf1[:, ch*128..]) ----
        f32x4 a[8];
#pragma unroll
        for (int j = 0; j < 8; j++) a[j] = (f32x4){0.f, 0.f, 0.f, 0.f};
#pragma unroll
        for (int ks = 0; ks < 4; ks++) {
            int byte = (lrow * 256 + ks * 64 + lq * 16) ^ ((lrow & 7) << 4);
            bf16x8 af = *(const bf16x8*)&Xw[byte];
#pragma unroll
            for (int j = 0; j < 8; j++) {
                int jc = ch * 8 + j;
                bf16x8 bq = *(const bf16x8*)&Wf1pk[(((size_t)ks * 32 + jc) * 64 + l) * 8];
                a[j] = __builtin_amdgcn_mfma_f32_16x16x32_bf16(af, bq, a[j], 0, 0, 0);
            }
        }
#pragma unroll
        for (int j = 0; j < 8; j++) {
            float bias = bf1[ch * 128 + j * 16 + lrow];
#pragma unroll
            for (int q = 0; q < 4; q++) {
                float v = fmaxf(a[j][q] + bias, 0.f);
                int row = lq * 4 + q;
                int col = j * 16 + lrow;
                int byte = (row * 256 + col * 2) ^ ((row & 7) << 4);
                *(unsigned short*)&Hw[byte] = f2bf(v);
            }
        }
        // ---- phase B: oacc += H_chunk @ Wf2[ch*128.., :] (same-wave LDS dep only) ----
#pragma unroll
        for (int ks = 0; ks < 4; ks++) {
            int byte = (lrow * 256 + ks * 64 + lq * 16) ^ ((lrow & 7) << 4);
            bf16x8 hf = *(const bf16x8*)&Hw[byte];
            int kt = ch * 4 + ks;
#pragma unroll
            for (int j = 0; j < 8; j++) {
                bf16x8 b2 = *(const bf16x8*)&Wf2pk[(((size_t)kt * 8 + j) * 64 + l) * 8];
                oacc[j] = __builtin_amdgcn_mfma_f32_16x16x32_bf16(hf, b2, oacc[j], 0, 0, 0);
            }
        }
    }

    // ---- in-register LN epilogue ----
    // lane holds rows lq*4+q (q 0..3), cols j*16+lrow (j 0..7)
    float bcol[8], gcol[8], becol[8];
#pragma unroll
    for (int j = 0; j < 8; j++) {
        int col = j * 16 + lrow;
        bcol[j] = bf2[col];
        gcol[j] = g3[col];
        becol[j] = be3[col];
    }
    float sum[4], sq[4];
#pragma unroll
    for (int q = 0; q < 4; q++) {
        float s = 0.f, qq = 0.f;
#pragma unroll
        for (int j = 0; j < 8; j++) {
            float x = oacc[j][q] + bcol[j];
            s += x;
            qq += x * x;
        }
        sum[q] = s;
        sq[q] = qq;
    }
#pragma unroll
    for (int m = 1; m < 16; m <<= 1) {
#pragma unroll
        for (int q = 0; q < 4; q++) {
            sum[q] += __shfl_xor(sum[q], m, 64);
            sq[q]  += __shfl_xor(sq[q], m, 64);
        }
    }
#pragma unroll
    for (int q = 0; q < 4; q++) {
        int n = rowbase + lq * 4 + q;
        if (n >= NN) continue;
        float mu = sum[q] * (1.f / 128.f);
        float var = (sq[q] - 128.f * mu * mu) * (1.f / 127.f);
        float sd = sqrtf(fmaxf(var, 0.f));
        float inv = 1.f / (sd + 1e-6f);
#pragma unroll
        for (int j = 0; j < 8; j++) {
            int col = j * 16 + lrow;
            float x = oacc[j][q] + bcol[j];
            float y = gcol[j] * (x - mu) * inv + becol[j];
            y = (y > 0.f) ? y : 0.01f * y;
            float r = X[(size_t)n * DD + col];
            out[(size_t)n * DD + col] = r + y;
        }
    }
}

extern "C" void kernel_launch(void* const* d_in, const int* in_sizes, int n_in,
                              void* d_out, int out_size, void* d_ws, size_t ws_size,
                              hipStream_t stream) {
    const float* nf  = (const float*)d_in[0];
    const int*   ei  = (const int*)d_in[1];
    const float* ew  = (const float*)d_in[2];
    const float* W1  = (const float*)d_in[3];
    const float* as1 = (const float*)d_in[4];
    const float* ad1 = (const float*)d_in[5];
    const float* We1 = (const float*)d_in[6];
    const float* ae1 = (const float*)d_in[7];
    const float* b1  = (const float*)d_in[8];
    const float* g1  = (const float*)d_in[9];
    const float* be1 = (const float*)d_in[10];
    const float* W2  = (const float*)d_in[11];
    const float* as2 = (const float*)d_in[12];
    const float* ad2 = (const float*)d_in[13];
    const float* We2 = (const float*)d_in[14];
    const float* ae2 = (const float*)d_in[15];
    const float* b2  = (const float*)d_in[16];
    const float* g2  = (const float*)d_in[17];
    const float* be2 = (const float*)d_in[18];
    const float* Wf1 = (const float*)d_in[19];
    const float* bf1 = (const float*)d_in[20];
    const float* Wf2 = (const float*)d_in[21];
    const float* bf2 = (const float*)d_in[22];
    const float* g3  = (const float*)d_in[23];
    const float* be3 = (const float*)d_in[24];
    float* out = (float*)d_out;

    char* p = (char*)d_ws;
    auto alloc = [&](size_t bytes) {
        char* r = p;
        p += (bytes + 255) & ~(size_t)255;
        return r;
    };
    float* nf_cur = (float*)alloc((size_t)NN * DD * 4);
    unsigned short* xh_bf = (unsigned short*)alloc((size_t)NN * DD * 2);
    unsigned short* s_e1  = (unsigned short*)alloc((size_t)NE * HH * 2);
    unsigned short* s_e2  = (unsigned short*)alloc((size_t)NE * HH * 2);
    unsigned short* s_srcb = (unsigned short*)alloc((size_t)NN * HH * 2);
    float* s_dst  = (float*)alloc((size_t)NN * HH * 4);
    int* row_start = (int*)alloc((size_t)(NN + 1) * 4);
    int* cnt       = (int*)alloc((size_t)NN * 4);
    int* cursor    = (int*)alloc((size_t)NN * 4);
    int* partials  = (int*)alloc((size_t)SCAN_NB * 4);
    int* bucket_cursor = (int*)alloc((size_t)NBKT * 4);
    int2* binned   = (int2*)alloc((size_t)NE * 8);
    int* e_src     = (int*)alloc((size_t)NE * 4);
    int* e_eid     = (int*)alloc((size_t)NE * 4);
    unsigned short* W1pk  = (unsigned short*)alloc((size_t)DD * DD * 2);
    unsigned short* W2pk  = (unsigned short*)alloc((size_t)DD * DD * 2);
    unsigned short* Wf1pk = (unsigned short*)alloc((size_t)DD * DFF * 2);
    unsigned short* Wf2pk = (unsigned short*)alloc((size_t)DFF * DD * 2);

    int ebl = (NE + 255) / 256;
    int nbl = (NN + 255) / 256;

    // weight pack+cvt (tiny, once): fragment-order bf16
    cvtpack_k<<<(DD * DD + 255) / 256, 256, 0, stream>>>(W1, W1pk, DD, DD);
    cvtpack_k<<<(DD * DD + 255) / 256, 256, 0, stream>>>(W2, W2pk, DD, DD);
    cvtpack_k<<<(DD * DFF + 255) / 256, 256, 0, stream>>>(Wf1, Wf1pk, DD, DFF);
    cvtpack_k<<<(DD * DFF + 255) / 256, 256, 0, stream>>>(Wf2, Wf2pk, DFF, DD);

    // CSR build (hierarchical scan)
    zero_int_k<<<nbl, 256, 0, stream>>>(cnt, NN);
    count_k<<<ebl, 256, 0, stream>>>(ei + NE, cnt);
    blksum_k<<<SCAN_NB, 256, 0, stream>>>(cnt, partials);
    scanpart_k<<<1, 256, 0, stream>>>(partials);
    scanapply_k<<<SCAN_NB, 256, 0, stream>>>(cnt, partials, row_start, cursor);

    // two-level binned scatter (kills cross-XCD write amplification)
    bucketbase_k<<<(NBKT + 255) / 256, 256, 0, stream>>>(row_start, bucket_cursor);
    bin_k<<<(NE + EPB - 1) / EPB, 256, 0, stream>>>(ei, bucket_cursor, binned);
    csr_scatter_k<<<NBKT, 256, 0, stream>>>(binned, row_start, cursor, e_src, e_eid);

    // edge scores for BOTH layers, coalesced bf16 writes
    se2_k<<<ebl, 256, 0, stream>>>(ew, e_eid, We1, ae1, We2, ae2, s_e1, s_e2);

    int gbl = (NN + 127) / 128;
    int wbl = (NN + 3) / 4;
    int sbl = (NN * HH + 255) / 256;

    // ---- GAT layer 1 ----
    gemm_mfma_k<<<gbl, 256, 0, stream>>>(nf, W1pk, xh_bf);
    ssd_k<<<sbl, 256, 0, stream>>>(xh_bf, as1, ad1, s_srcb, s_dst);
    agg_ln_k<<<wbl, 256, 0, stream>>>(row_start, e_src, s_srcb, s_dst, s_e1, xh_bf,
                                      b1, g1, be1, nf, nf_cur);

    // ---- GAT layer 2 ----
    gemm_mfma_k<<<gbl, 256, 0, stream>>>(nf_cur, W2pk, xh_bf);
    ssd_k<<<sbl, 256, 0, stream>>>(xh_bf, as2, ad2, s_srcb, s_dst);
    agg_ln_k<<<wbl, 256, 0, stream>>>(row_start, e_src, s_srcb, s_dst, s_e2, xh_bf,
                                      b2, g2, be2, nf_cur, nf_cur);

    // ---- FFN + final LN (fused, barrier-free) ----
    ffn_ln_k<<<(NN + 63) / 64, 256, 0, stream>>>(nf_cur, Wf1pk, bf1, Wf2pk,
                                                 bf2, g3, be3, out);
}

// Round 15
// 285.006 us; speedup vs baseline: 1.0627x; 1.0031x over previous
//
#include <hip/hip_runtime.h>
#include <hip/hip_bf16.h>

#define NN 50000
#define NE 800000
#define DD 128
#define HH 8
#define CC 16
#define DFF 512
#define ED 16
#define SCAN_NB ((NN + 255) / 256)   // 196
#define BKT 256
#define NBKT ((NN + BKT - 1) / BKT)  // 196
#define EPB 4096

typedef __attribute__((ext_vector_type(8))) short bf16x8;
typedef __attribute__((ext_vector_type(4))) float f32x4;

union U8 { bf16x8 v; unsigned short s[8]; };

__device__ inline unsigned short f2bf(float f) {
    union { float f; unsigned u; } v; v.f = f;
    return (unsigned short)((v.u + 0x7fffu + ((v.u >> 16) & 1u)) >> 16);
}
__device__ inline float bf2f(unsigned s) {
    union { unsigned u; float f; } v; v.u = s << 16;
    return v.f;
}

// ---------------- utility ----------------
__global__ void zero_int_k(int* __restrict__ a, int n) {
    int i = blockIdx.x * 256 + threadIdx.x;
    if (i < n) a[i] = 0;
}

// pack weights into MFMA B-fragment order
__global__ void cvtpack_k(const float* __restrict__ W, unsigned short* __restrict__ Wpk,
                          int K, int N) {
    int idx = blockIdx.x * 256 + threadIdx.x;
    if (idx >= K * N) return;
    int e = idx & 7;
    int l = (idx >> 3) & 63;
    int r = idx >> 9;
    int n16 = N >> 4;
    int jc = r % n16;
    int kt = r / n16;
    int k = kt * 32 + (l >> 4) * 8 + e;
    int n = jc * 16 + (l & 15);
    Wpk[idx] = f2bf(W[(size_t)k * N + n]);
}

// ---------------- CSR build ----------------
__global__ void count_k(const int* __restrict__ dst, int* __restrict__ cnt) {
    int e = blockIdx.x * 256 + threadIdx.x;
    if (e < NE) atomicAdd(&cnt[dst[e]], 1);
}

__global__ void blksum_k(const int* __restrict__ cnt, int* __restrict__ partials) {
    int i = blockIdx.x * 256 + threadIdx.x;
    int v = (i < NN) ? cnt[i] : 0;
#pragma unroll
    for (int m = 1; m < 64; m <<= 1) v += __shfl_xor(v, m, 64);
    __shared__ int ws[4];
    if ((threadIdx.x & 63) == 0) ws[threadIdx.x >> 6] = v;
    __syncthreads();
    if (threadIdx.x == 0) partials[blockIdx.x] = ws[0] + ws[1] + ws[2] + ws[3];
}

__global__ void scanpart_k(int* __restrict__ partials) {
    __shared__ int buf[256];
    int t = threadIdx.x;
    int v = (t < SCAN_NB) ? partials[t] : 0;
    buf[t] = v;
    __syncthreads();
    for (int off = 1; off < 256; off <<= 1) {
        int u = (t >= off) ? buf[t - off] : 0;
        __syncthreads();
        buf[t] += u;
        __syncthreads();
    }
    if (t < SCAN_NB) partials[t] = buf[t] - v;  // exclusive
}

// block-local scan + offsets -> row_start, cursor, and bucket_cursor (fused)
__global__ void scanapply_k(const int* __restrict__ cnt, const int* __restrict__ partials,
                            int* __restrict__ row_start, int* __restrict__ cursor,
                            int* __restrict__ bucket_cursor) {
    __shared__ int buf[256];
    int t = threadIdx.x;
    int i = blockIdx.x * 256 + t;
    int v = (i < NN) ? cnt[i] : 0;
    buf[t] = v;
    __syncthreads();
    for (int off = 1; off < 256; off <<= 1) {
        int u = (t >= off) ? buf[t - off] : 0;
        __syncthreads();
        buf[t] += u;
        __syncthreads();
    }
    int excl = buf[t] - v + partials[blockIdx.x];
    if (i < NN) {
        row_start[i] = excl;
        cursor[i] = excl;
        if (t == 0) bucket_cursor[blockIdx.x] = excl;   // == row_start[b*256]
        if (i == NN - 1) row_start[NN] = excl + v;
    }
}

// pass A: bin edges into bucket-major order with LDS-chunked (burst) writes
__global__ __launch_bounds__(256) void bin_k(const int* __restrict__ ei,
                                             int* __restrict__ bucket_cursor,
                                             int2* __restrict__ binned) {
    __shared__ int hist[NBKT];
    __shared__ int base[NBKT];
    int t = threadIdx.x;
    int e0 = blockIdx.x * EPB;
    int eend = e0 + EPB; if (eend > NE) eend = NE;
    if (t < NBKT) hist[t] = 0;
    __syncthreads();
    for (int e = e0 + t; e < eend; e += 256) {
        int d = ei[NE + e];
        atomicAdd(&hist[d >> 8], 1);
    }
    __syncthreads();
    if (t < NBKT) {
        int c = hist[t];
        base[t] = c ? atomicAdd(&bucket_cursor[t], c) : 0;
        hist[t] = 0;   // reuse as local cursor
    }
    __syncthreads();
    for (int e = e0 + t; e < eend; e += 256) {
        int s = ei[e];
        int d = ei[NE + e];
        int b = d >> 8;
        int loc = atomicAdd(&hist[b], 1);
        binned[base[b] + loc] = make_int2(s | ((d & 255) << 16), e);
    }
}

// pass B: per-bucket CSR scatter (SoA outputs: e_src for agg, e_eid for se2)
__global__ __launch_bounds__(256) void csr_scatter_k(const int2* __restrict__ binned,
                                                     const int* __restrict__ row_start,
                                                     int* __restrict__ cursor,
                                                     int* __restrict__ e_src,
                                                     int* __restrict__ e_eid) {
    int b = blockIdx.x;
    int beg = row_start[b * BKT];
    int endNode = (b + 1) * BKT; if (endNode > NN) endNode = NN;
    int end = row_start[endNode];
    for (int p = beg + threadIdx.x; p < end; p += 256) {
        int2 r = binned[p];
        int d = b * BKT + (r.x >> 16);
        int pos = atomicAdd(&cursor[d], 1);
        e_src[pos] = r.x & 0xffff;
        e_eid[pos] = r.y;
    }
}

// ---------------- edge scores, both layers, CSR order, bf16 output ----------------
__global__ void se2_k(const float* __restrict__ ew, const int* __restrict__ e_eid,
                      const float* __restrict__ We1, const float* __restrict__ ae1,
                      const float* __restrict__ We2, const float* __restrict__ ae2,
                      unsigned short* __restrict__ s_e1, unsigned short* __restrict__ s_e2) {
    __shared__ float A1[ED * HH], A2[ED * HH];
    int t = threadIdx.x;
    if (t < 128) {
        int k = t >> 3, h = t & 7;
        float s = 0.f;
#pragma unroll
        for (int c = 0; c < CC; c++) s += We1[k * DD + h * CC + c] * ae1[h * CC + c];
        A1[t] = s;
    } else {
        int u = t - 128;
        int k = u >> 3, h = u & 7;
        float s = 0.f;
#pragma unroll
        for (int c = 0; c < CC; c++) s += We2[k * DD + h * CC + c] * ae2[h * CC + c];
        A2[u] = s;
    }
    __syncthreads();
    int p = blockIdx.x * 256 + t;
    if (p >= NE) return;
    int eid = e_eid[p];
    const float* ep = &ew[(size_t)eid * ED];
    float4 v0 = *(const float4*)(ep);
    float4 v1 = *(const float4*)(ep + 4);
    float4 v2 = *(const float4*)(ep + 8);
    float4 v3 = *(const float4*)(ep + 12);
    float ev[16] = {v0.x, v0.y, v0.z, v0.w, v1.x, v1.y, v1.z, v1.w,
                    v2.x, v2.y, v2.z, v2.w, v3.x, v3.y, v3.z, v3.w};
    float o1[8] = {0, 0, 0, 0, 0, 0, 0, 0};
    float o2[8] = {0, 0, 0, 0, 0, 0, 0, 0};
#pragma unroll
    for (int k = 0; k < 16; k++) {
        float v = ev[k];
#pragma unroll
        for (int h = 0; h < 8; h++) {
            o1[h] += v * A1[k * 8 + h];
            o2[h] += v * A2[k * 8 + h];
        }
    }
    U8 w1, w2;
#pragma unroll
    for (int h = 0; h < 8; h++) { w1.s[h] = f2bf(o1[h]); w2.s[h] = f2bf(o2[h]); }
    *(bf16x8*)&s_e1[(size_t)p * 8] = w1.v;
    *(bf16x8*)&s_e2[(size_t)p * 8] = w2.v;
}

// ---------------- MFMA node GEMM: Ybf = bf16(X @ W), W packed in fragment order ----------------
__global__ __launch_bounds__(256) void gemm_mfma_k(const float* __restrict__ X,
                                                   const unsigned short* __restrict__ Wpk,
                                                   unsigned short* __restrict__ Ybf) {
    __shared__ char Xl[128 * 256];  // bf16 [row][128], XOR-swizzled
    int t = threadIdx.x;
    int nb0 = blockIdx.x * 128;
    for (int c = t; c < 2048; c += 256) {
        int row = c >> 4, cb = c & 15;
        int n = nb0 + row;
        U8 u;
        if (n < NN) {
            const float* xp = &X[(size_t)n * DD + cb * 8];
            float4 a = *(const float4*)xp;
            float4 b = *(const float4*)(xp + 4);
            u.s[0] = f2bf(a.x); u.s[1] = f2bf(a.y); u.s[2] = f2bf(a.z); u.s[3] = f2bf(a.w);
            u.s[4] = f2bf(b.x); u.s[5] = f2bf(b.y); u.s[6] = f2bf(b.z); u.s[7] = f2bf(b.w);
        } else {
#pragma unroll
            for (int q = 0; q < 8; q++) u.s[q] = 0;
        }
        int byte = (row * 256 + cb * 16) ^ ((row & 7) << 4);
        *(bf16x8*)&Xl[byte] = u.v;
    }
    __syncthreads();
    int w = t >> 6, l = t & 63;
    int lrow = l & 15, lq = l >> 4;
    int r0 = (w & 1) * 64, c0 = (w >> 1) * 64;
    f32x4 acc[4][4];
#pragma unroll
    for (int i = 0; i < 4; i++)
#pragma unroll
        for (int j = 0; j < 4; j++) acc[i][j] = (f32x4){0.f, 0.f, 0.f, 0.f};
#pragma unroll
    for (int ks = 0; ks < 4; ks++) {
        int k0 = ks * 32;
        bf16x8 af[4], bq[4];
#pragma unroll
        for (int i = 0; i < 4; i++) {
            int rr = r0 + i * 16 + lrow;
            int byte = (rr * 256 + k0 * 2 + lq * 16) ^ ((rr & 7) << 4);
            af[i] = *(const bf16x8*)&Xl[byte];
        }
#pragma unroll
        for (int j = 0; j < 4; j++) {
            int j16 = (c0 >> 4) + j;
            bq[j] = *(const bf16x8*)&Wpk[(((size_t)ks * 8 + j16) * 64 + l) * 8];
        }
#pragma unroll
        for (int i = 0; i < 4; i++)
#pragma unroll
            for (int j = 0; j < 4; j++)
                acc[i][j] = __builtin_amdgcn_mfma_f32_16x16x32_bf16(af[i], bq[j], acc[i][j], 0, 0, 0);
    }
#pragma unroll
    for (int i = 0; i < 4; i++) {
#pragma unroll
        for (int j = 0; j < 4; j++) {
#pragma unroll
            for (int q = 0; q < 4; q++) {
                int n = nb0 + r0 + i * 16 + lq * 4 + q;
                if (n < NN) Ybf[(size_t)n * DD + c0 + j * 16 + lrow] = f2bf(acc[i][j][q]);
            }
        }
    }
}

// ---------------- s_src(bf16)/s_dst(f32) from bf16 xh ----------------
__global__ void ssd_k(const unsigned short* __restrict__ xh_bf, const float* __restrict__ a_src,
                      const float* __restrict__ a_dst, unsigned short* __restrict__ s_srcb,
                      float* __restrict__ s_dst) {
    __shared__ float as[128], ad[128];
    if (threadIdx.x < 128) {
        as[threadIdx.x] = a_src[threadIdx.x];
        ad[threadIdx.x] = a_dst[threadIdx.x];
    }
    __syncthreads();
    int idx = blockIdx.x * 256 + threadIdx.x;
    if (idx >= NN * HH) return;
    int n = idx >> 3, h = idx & 7;
    const unsigned short* x = &xh_bf[(size_t)n * DD + h * CC];
    U8 u0, u1;
    u0.v = *(const bf16x8*)(x);
    u1.v = *(const bf16x8*)(x + 8);
    float s1 = 0.f, s2 = 0.f;
#pragma unroll
    for (int c = 0; c < 8; c++) {
        float v = bf2f(u0.s[c]);
        s1 += v * as[h * CC + c];
        s2 += v * ad[h * CC + c];
    }
#pragma unroll
    for (int c = 0; c < 8; c++) {
        float v = bf2f(u1.s[c]);
        s1 += v * as[h * CC + 8 + c];
        s2 += v * ad[h * CC + 8 + c];
    }
    s_srcb[idx] = f2bf(s1);
    s_dst[idx] = s2;
}

// ---------------- fused aggregation + bias + LayerNorm + leaky + residual ----------------
// bf16 message gather (256B/edge); 8 edges/iter score dedup via shfl.
__global__ __launch_bounds__(256) void agg_ln_k(const int* __restrict__ row_start,
                                                const int* __restrict__ e_src,
                                                const unsigned short* __restrict__ s_srcb,
                                                const float* __restrict__ s_dst,
                                                const unsigned short* __restrict__ s_eb,
                                                const unsigned short* __restrict__ xh_bf,
                                                const float* __restrict__ bias,
                                                const float* __restrict__ g,
                                                const float* __restrict__ be,
                                                const float* __restrict__ res,
                                                float* __restrict__ outNf) {
    int wid = (blockIdx.x * 256 + threadIdx.x) >> 6;
    if (wid >= NN) return;
    int lane = threadIdx.x & 63;
    int h = lane >> 3;
    int k = lane & 7;
    unsigned h2 = (unsigned)h << 1;
    unsigned loff = (unsigned)lane << 2;
    const char* xb = (const char*)xh_bf;
    const char* sb = (const char*)s_srcb;
    const char* eb = (const char*)s_eb;
    float sdst = s_dst[wid * 8 + h];
    int beg = row_start[wid], end = row_start[wid + 1];
    float acc0 = 0.f, acc1 = 0.f, zpart = 0.f, ztail = 0.f;
    int p = beg;
    int bcast = h << 3;
    for (; p + 8 <= end; p += 8) {
        unsigned q = (unsigned)e_src[p + k];
        float vs = bf2f(*(const unsigned short*)(sb + (q << 4) + h2));
        float ve = bf2f(*(const unsigned short*)(eb + (((unsigned)(p + k)) << 4) + h2));
        float a = vs + sdst + ve;
        a = fmaxf(a, 0.2f * a);
        float esc = __expf(a);
        zpart += esc;
#pragma unroll
        for (int kk = 0; kk < 8; kk++) {
            float sck = __shfl(esc, bcast + kk, 64);
            unsigned qk = (unsigned)__shfl((int)q, kk, 64);
            unsigned u = *(const unsigned*)(xb + (qk << 8) + loff);
            acc0 = fmaf(sck, bf2f(u & 0xffffu), acc0);
            acc1 = fmaf(sck, bf2f(u >> 16), acc1);
        }
    }
    for (; p < end; p++) {
        unsigned q0 = (unsigned)e_src[p];
        float a0 = bf2f(*(const unsigned short*)(sb + (q0 << 4) + h2)) + sdst
                 + bf2f(*(const unsigned short*)(eb + ((unsigned)p << 4) + h2));
        unsigned u0 = *(const unsigned*)(xb + (q0 << 8) + loff);
        a0 = fmaxf(a0, 0.2f * a0);
        float e0 = __expf(a0);
        ztail += e0;
        acc0 = fmaf(e0, bf2f(u0 & 0xffffu), acc0);
        acc1 = fmaf(e0, bf2f(u0 >> 16), acc1);
    }
    float z = zpart;
    z += __shfl_xor(z, 1, 64);
    z += __shfl_xor(z, 2, 64);
    z += __shfl_xor(z, 4, 64);
    z += ztail;
    float inv = 1.f / (z + 1e-16f);
    float2 b = *(const float2*)&bias[lane * 2];
    float x0 = acc0 * inv + b.x;
    float x1 = acc1 * inv + b.y;
    float s = x0 + x1;
    float q = x0 * x0 + x1 * x1;
#pragma unroll
    for (int m = 1; m < 64; m <<= 1) {
        s += __shfl_xor(s, m, 64);
        q += __shfl_xor(q, m, 64);
    }
    float mu = s * (1.f / 128.f);
    float var = (q - 128.f * mu * mu) * (1.f / 127.f);
    float sd = sqrtf(fmaxf(var, 0.f));
    float invs = 1.f / (sd + 1e-6f);
    float2 gg = *(const float2*)&g[lane * 2];
    float2 bb = *(const float2*)&be[lane * 2];
    float y0 = gg.x * (x0 - mu) * invs + bb.x;
    float y1 = gg.y * (x1 - mu) * invs + bb.y;
    y0 = (y0 > 0.f) ? y0 : 0.01f * y0;
    y1 = (y1 > 0.f) ? y1 : 0.01f * y1;
    float2 r = *(const float2*)&res[(size_t)wid * DD + lane * 2];
    *(float2*)&outNf[(size_t)wid * DD + lane * 2] = make_float2(r.x + y0, r.y + y1);
}

// ---------------- barrier-free fused FFN + LN: wave-private 16-node slices ----------------
__global__ __launch_bounds__(256) void ffn_ln_k(const float* __restrict__ X,
                                                const unsigned short* __restrict__ Wf1pk,
                                                const float* __restrict__ bf1,
                                                const unsigned short* __restrict__ Wf2pk,
                                                const float* __restrict__ bf2,
                                                const float* __restrict__ g3,
                                                const float* __restrict__ be3,
                                                float* __restrict__ out) {
    __shared__ char LDSBUF[32768];   // per-wave: Xl at w*4096, Hl at 16384+w*4096
    int t = threadIdx.x;
    int w = t >> 6, l = t & 63;
    int lrow = l & 15, lq = l >> 4;
    int nb0 = blockIdx.x * 64;
    int rowbase = nb0 + w * 16;
    char* Xw = LDSBUF + w * 4096;
    char* Hw = LDSBUF + 16384 + w * 4096;

    for (int c = l; c < 256; c += 64) {
        int row = c >> 4, cb = c & 15;
        int n = rowbase + row;
        U8 u;
        if (n < NN) {
            const float* xp = &X[(size_t)n * DD + cb * 8];
            float4 a = *(const float4*)xp;
            float4 b = *(const float4*)(xp + 4);
            u.s[0] = f2bf(a.x); u.s[1] = f2bf(a.y); u.s[2] = f2bf(a.z); u.s[3] = f2bf(a.w);
            u.s[4] = f2bf(b.x); u.s[5] = f2bf(b.y); u.s[6] = f2bf(b.z); u.s[7] = f2bf(b.w);
        } else {
#pragma unroll
            for (int q = 0; q < 8; q++) u.s[q] = 0;
        }
        int byte = (row * 256 + cb * 16) ^ ((row & 7) << 4);
        *(bf16x8*)&Xw[byte] = u.v;
    }

    f32x4 oacc[8];
#pragma unroll
    for (int j = 0; j < 8; j++) oacc[j] = (f32x4){0.f, 0.f, 0.f, 0.f};

#pragma unroll
    for (int ch = 0; ch < 4; ch++) {
        f32x4 a[8];
#pragma unroll
        for (int j = 0; j < 8; j++) a[j] = (f32x4){0.f, 0.f, 0.f, 0.f};
#pragma unroll
        for (int ks = 0; ks < 4; ks++) {
            int byte = (lrow * 256 + ks * 64 + lq * 16) ^ ((lrow & 7) << 4);
            bf16x8 af = *(const bf16x8*)&Xw[byte];
#pragma unroll
            for (int j = 0; j < 8; j++) {
                int jc = ch * 8 + j;
                bf16x8 bq = *(const bf16x8*)&Wf1pk[(((size_t)ks * 32 + jc) * 64 + l) * 8];
                a[j] = __builtin_amdgcn_mfma_f32_16x16x32_bf16(af, bq, a[j], 0, 0, 0);
            }
        }
#pragma unroll
        for (int j = 0; j < 8; j++) {
            float bias = bf1[ch * 128 + j * 16 + lrow];
#pragma unroll
            for (int q = 0; q < 4; q++) {
                float v = fmaxf(a[j][q] + bias, 0.f);
                int row = lq * 4 + q;
                int col = j * 16 + lrow;
                int byte = (row * 256 + col * 2) ^ ((row & 7) << 4);
                *(unsigned short*)&Hw[byte] = f2bf(v);
            }
        }
#pragma unroll
        for (int ks = 0; ks < 4; ks++) {
            int byte = (lrow * 256 + ks * 64 + lq * 16) ^ ((lrow & 7) << 4);
            bf16x8 hf = *(const bf16x8*)&Hw[byte];
            int kt = ch * 4 + ks;
#pragma unroll
            for (int j = 0; j < 8; j++) {
                bf16x8 b2 = *(const bf16x8*)&Wf2pk[(((size_t)kt * 8 + j) * 64 + l) * 8];
                oacc[j] = __builtin_amdgcn_mfma_f32_16x16x32_bf16(hf, b2, oacc[j], 0, 0, 0);
            }
        }
    }

    float bcol[8], gcol[8], becol[8];
#pragma unroll
    for (int j = 0; j < 8; j++) {
        int col = j * 16 + lrow;
        bcol[j] = bf2[col];
        gcol[j] = g3[col];
        becol[j] = be3[col];
    }
    float sum[4], sq[4];
#pragma unroll
    for (int q = 0; q < 4; q++) {
        float s = 0.f, qq = 0.f;
#pragma unroll
        for (int j = 0; j < 8; j++) {
            float x = oacc[j][q] + bcol[j];
            s += x;
            qq += x * x;
        }
        sum[q] = s;
        sq[q] = qq;
    }
#pragma unroll
    for (int m = 1; m < 16; m <<= 1) {
#pragma unroll
        for (int q = 0; q < 4; q++) {
            sum[q] += __shfl_xor(sum[q], m, 64);
            sq[q]  += __shfl_xor(sq[q], m, 64);
        }
    }
#pragma unroll
    for (int q = 0; q < 4; q++) {
        int n = rowbase + lq * 4 + q;
        if (n >= NN) continue;
        float mu = sum[q] * (1.f / 128.f);
        float var = (sq[q] - 128.f * mu * mu) * (1.f / 127.f);
        float sd = sqrtf(fmaxf(var, 0.f));
        float inv = 1.f / (sd + 1e-6f);
#pragma unroll
        for (int j = 0; j < 8; j++) {
            int col = j * 16 + lrow;
            float x = oacc[j][q] + bcol[j];
            float y = gcol[j] * (x - mu) * inv + becol[j];
            y = (y > 0.f) ? y : 0.01f * y;
            float r = X[(size_t)n * DD + col];
            out[(size_t)n * DD + col] = r + y;
        }
    }
}

extern "C" void kernel_launch(void* const* d_in, const int* in_sizes, int n_in,
                              void* d_out, int out_size, void* d_ws, size_t ws_size,
                              hipStream_t stream) {
    const float* nf  = (const float*)d_in[0];
    const int*   ei  = (const int*)d_in[1];
    const float* ew  = (const float*)d_in[2];
    const float* W1  = (const float*)d_in[3];
    const float* as1 = (const float*)d_in[4];
    const float* ad1 = (const float*)d_in[5];
    const float* We1 = (const float*)d_in[6];
    const float* ae1 = (const float*)d_in[7];
    const float* b1  = (const float*)d_in[8];
    const float* g1  = (const float*)d_in[9];
    const float* be1 = (const float*)d_in[10];
    const float* W2  = (const float*)d_in[11];
    const float* as2 = (const float*)d_in[12];
    const float* ad2 = (const float*)d_in[13];
    const float* We2 = (const float*)d_in[14];
    const float* ae2 = (const float*)d_in[15];
    const float* b2  = (const float*)d_in[16];
    const float* g2  = (const float*)d_in[17];
    const float* be2 = (const float*)d_in[18];
    const float* Wf1 = (const float*)d_in[19];
    const float* bf1 = (const float*)d_in[20];
    const float* Wf2 = (const float*)d_in[21];
    const float* bf2 = (const float*)d_in[22];
    const float* g3  = (const float*)d_in[23];
    const float* be3 = (const float*)d_in[24];
    float* out = (float*)d_out;

    char* p = (char*)d_ws;
    auto alloc = [&](size_t bytes) {
        char* r = p;
        p += (bytes + 255) & ~(size_t)255;
        return r;
    };
    float* nf_cur = (float*)alloc((size_t)NN * DD * 4);
    unsigned short* xh_bf = (unsigned short*)alloc((size_t)NN * DD * 2);
    unsigned short* s_e1  = (unsigned short*)alloc((size_t)NE * HH * 2);
    unsigned short* s_e2  = (unsigned short*)alloc((size_t)NE * HH * 2);
    unsigned short* s_srcb = (unsigned short*)alloc((size_t)NN * HH * 2);
    float* s_dst  = (float*)alloc((size_t)NN * HH * 4);
    int* row_start = (int*)alloc((size_t)(NN + 1) * 4);
    int* cnt       = (int*)alloc((size_t)NN * 4);
    int* cursor    = (int*)alloc((size_t)NN * 4);
    int* partials  = (int*)alloc((size_t)SCAN_NB * 4);
    int* bucket_cursor = (int*)alloc((size_t)NBKT * 4);
    int2* binned   = (int2*)alloc((size_t)NE * 8);
    int* e_src     = (int*)alloc((size_t)NE * 4);
    int* e_eid     = (int*)alloc((size_t)NE * 4);
    unsigned short* W1pk  = (unsigned short*)alloc((size_t)DD * DD * 2);
    unsigned short* W2pk  = (unsigned short*)alloc((size_t)DD * DD * 2);
    unsigned short* Wf1pk = (unsigned short*)alloc((size_t)DD * DFF * 2);
    unsigned short* Wf2pk = (unsigned short*)alloc((size_t)DFF * DD * 2);

    int ebl = (NE + 255) / 256;
    int nbl = (NN + 255) / 256;

    // weight pack+cvt (tiny, once): fragment-order bf16
    cvtpack_k<<<(DD * DD + 255) / 256, 256, 0, stream>>>(W1, W1pk, DD, DD);
    cvtpack_k<<<(DD * DD + 255) / 256, 256, 0, stream>>>(W2, W2pk, DD, DD);
    cvtpack_k<<<(DD * DFF + 255) / 256, 256, 0, stream>>>(Wf1, Wf1pk, DD, DFF);
    cvtpack_k<<<(DD * DFF + 255) / 256, 256, 0, stream>>>(Wf2, Wf2pk, DFF, DD);

    // CSR build (hierarchical scan; bucketbase fused into scanapply)
    zero_int_k<<<nbl, 256, 0, stream>>>(cnt, NN);
    count_k<<<ebl, 256, 0, stream>>>(ei + NE, cnt);
    blksum_k<<<SCAN_NB, 256, 0, stream>>>(cnt, partials);
    scanpart_k<<<1, 256, 0, stream>>>(partials);
    scanapply_k<<<SCAN_NB, 256, 0, stream>>>(cnt, partials, row_start, cursor, bucket_cursor);

    // two-level binned scatter
    bin_k<<<(NE + EPB - 1) / EPB, 256, 0, stream>>>(ei, bucket_cursor, binned);
    csr_scatter_k<<<NBKT, 256, 0, stream>>>(binned, row_start, cursor, e_src, e_eid);

    // edge scores for BOTH layers, coalesced bf16 writes
    se2_k<<<ebl, 256, 0, stream>>>(ew, e_eid, We1, ae1, We2, ae2, s_e1, s_e2);

    int gbl = (NN + 127) / 128;
    int wbl = (NN + 3) / 4;
    int sbl = (NN * HH + 255) / 256;

    // ---- GAT layer 1 ----
    gemm_mfma_k<<<gbl, 256, 0, stream>>>(nf, W1pk, xh_bf);
    ssd_k<<<sbl, 256, 0, stream>>>(xh_bf, as1, ad1, s_srcb, s_dst);
    agg_ln_k<<<wbl, 256, 0, stream>>>(row_start, e_src, s_srcb, s_dst, s_e1, xh_bf,
                                      b1, g1, be1, nf, nf_cur);

    // ---- GAT layer 2 ----
    gemm_mfma_k<<<gbl, 256, 0, stream>>>(nf_cur, W2pk, xh_bf);
    ssd_k<<<sbl, 256, 0, stream>>>(xh_bf, as2, ad2, s_srcb, s_dst);
    agg_ln_k<<<wbl, 256, 0, stream>>>(row_start, e_src, s_srcb, s_dst, s_e2, xh_bf,
                                      b2, g2, be2, nf_cur, nf_cur);

    // ---- FFN + final LN (fused, barrier-free) ----
    ffn_ln_k<<<(NN + 63) / 64, 256, 0, stream>>>(nf_cur, Wf1pk, bf1, Wf2pk,
                                                 bf2, g3, be3, out);
}